// Round 14
// baseline (3061.566 us; speedup 1.0000x reference)
//
#include <hip/hip_runtime.h>
#include <cstddef>

#define TOK   8192
#define DIMD  768
#define NH    12
#define DHD   64
#define SEQ   512
#define NB_   16
#define FFD   3072
#define NEXP  4
#define CCLS  10
#define FF2   (2*FFD)

typedef short bf16x8 __attribute__((ext_vector_type(8)));
typedef float f32x4  __attribute__((ext_vector_type(4)));

// ---------------- workspace layout (float-slot units) ----------------
static const size_t OFF_X    = 0;                                   // TOK*D fp32
static const size_t OFF_XB   = OFF_X   + (size_t)TOK*DIMD;          // TOK*D bf16
static const size_t OFF_F    = OFF_XB  + (size_t)TOK*DIMD/2;        // TOK*D bf16 (residual branch)
static const size_t OFF_SH   = OFF_F   + (size_t)TOK*DIMD;          // shared: Qb|Kb|Vb + G | Gglu
static const size_t SH_FL    = (size_t)8704*FF2/2;
static const size_t OFF_WQ   = OFF_SH  + SH_FL;                     // qkv weights bf16
static const size_t OFF_WOB  = OFF_WQ  + (size_t)3*DIMD*DIMD/2;
static const size_t OFF_W1B  = OFF_WOB + (size_t)DIMD*DIMD/2;       // up to 4 experts
static const size_t OFF_W2B  = OFF_W1B + (size_t)NEXP*FF2*DIMD/2;
static const size_t OFF_REP  = OFF_W2B + (size_t)NEXP*DIMD*FFD/2;
static const size_t OFF_HCLS = OFF_REP + (size_t)NB_*DIMD;
static const size_t OFF_STAT = OFF_HCLS+ (size_t)NB_*DIMD;          // sums[4]+pad
static const size_t OFF_INT  = OFF_STAT+ 8;                         // 160 int slots
static const size_t OFF_AUX  = OFF_INT + 160;
static const size_t OFF_EID  = OFF_AUX + 1;                         // TOK ints
static const size_t OFF_PERM = OFF_EID + TOK;                       // TOK ints

__device__ __forceinline__ ushort f2bf(float f) {
    union { float f; unsigned u; } v; v.f = f;
    unsigned r = v.u + 0x7FFF + ((v.u >> 16) & 1);   // RNE
    return (ushort)(r >> 16);
}
__device__ __forceinline__ float bf2f(ushort u) {
    union { unsigned u; float f; } v; v.u = ((unsigned)u) << 16;
    return v.f;
}
__device__ __forceinline__ void gload16(const void* g, void* l) {
    __builtin_amdgcn_global_load_lds((const __attribute__((address_space(1))) void*)g,
                                     (__attribute__((address_space(3))) void*)l, 16, 0, 0);
}

// chunked-bijective XCD swizzle (column-major walk) — R10-proven
__device__ __forceinline__ void xcd_swizzle_cm(int& bx, int& by)
{
    int gx = gridDim.x, gy = gridDim.y;
    int bid = blockIdx.x * gy + blockIdx.y;
    int nwg = gx * gy;
    int q = nwg >> 3, r8 = nwg & 7;
    int xcd = bid & 7, loc = bid >> 3;
    int lbid = (xcd < r8 ? xcd * (q + 1) : r8 * (q + 1) + (xcd - r8) * q) + loc;
    bx = lbid / gy;
    by = lbid % gy;
}

// ---------------- weight fp32 -> bf16 conversion ----------------
__global__ __launch_bounds__(256) void k_cvt(const float* __restrict__ s, ushort* __restrict__ d, int n8)
{
    int i = blockIdx.x * 256 + threadIdx.x;
    if (i >= n8) return;
    float4 x0 = ((const float4*)s)[i * 2];
    float4 x1 = ((const float4*)s)[i * 2 + 1];
    ushort r[8] = { f2bf(x0.x), f2bf(x0.y), f2bf(x0.z), f2bf(x0.w),
                    f2bf(x1.x), f2bf(x1.y), f2bf(x1.z), f2bf(x1.w) };
    ((uint4*)d)[i] = *(uint4*)r;
}

// ---------------- embedding: X fp32 + Xb bf16 ----------------
__global__ __launch_bounds__(256) void k_embed(const int* __restrict__ ids,
                                               const float* __restrict__ te,
                                               const float* __restrict__ pe,
                                               float* __restrict__ x,
                                               ushort* __restrict__ xb)
{
    int i = blockIdx.x * 256 + threadIdx.x;
    const int nd4 = DIMD / 4;
    if (i >= TOK * nd4) return;
    int t = i / nd4, d4 = i % nd4;
    int s = t % SEQ;
    int id = ids[t];
    float4 a = ((const float4*)(te + (size_t)id * DIMD))[d4];
    float4 b = ((const float4*)(pe + (size_t)s  * DIMD))[d4];
    float4 o; o.x = a.x + b.x; o.y = a.y + b.y; o.z = a.z + b.z; o.w = a.w + b.w;
    ((float4*)(x + (size_t)t * DIMD))[d4] = o;
    ushort4 ob = make_ushort4(f2bf(o.x), f2bf(o.y), f2bf(o.z), f2bf(o.w));
    *(ushort4*)(xb + (size_t)t * DIMD + d4 * 4) = ob;
}

// ---------------- 128x128 MFMA GEMM (R8/R10-proven 2-barrier loop) ----------------
template<int GATHER, int SCAT>
__global__ __launch_bounds__(256) void k_mm(const ushort* __restrict__ A,
                                            const ushort* __restrict__ Wb,
                                            const float* __restrict__ bias,
                                            ushort* __restrict__ C_,
                                            int N, int K, int lda,
                                            const int* __restrict__ perm,
                                            const int* __restrict__ offs,
                                            const int* __restrict__ blke,
                                            const int* __restrict__ blkb,
                                            const int* __restrict__ nblk)
{
    constexpr int MOE = GATHER || SCAT;
    __shared__ ushort As[2][4096];
    __shared__ ushort Bs[2][4096];
    __shared__ int    toks[128];
    const int tid = threadIdx.x, lane = tid & 63, w = tid >> 6;
    int bx, by;
    xcd_swizzle_cm(bx, by);
    const int n0 = bx * 128, row0 = by * 128;
    const ushort* W = Wb;
    const float*  bi = bias;
    int lb = 0, cnt = 1 << 30;
    if constexpr (MOE) {
        if (by >= *nblk) return;
        int e = blke[by];
        lb = blkb[by];
        int base = offs[e];
        cnt = offs[e + 1] - base;
        W  += (size_t)e * N * K;
        bi += (size_t)e * N;
        if (tid < 128) { int rg = lb + tid; toks[tid] = perm[base + (rg < cnt ? rg : cnt - 1)]; }
        __syncthreads();
    }
    int ar0, ar1;
    if constexpr (GATHER) { ar0 = toks[lane]; ar1 = toks[64 + lane]; }
    else                  { ar0 = row0 + lane; ar1 = row0 + 64 + lane; }
    const ushort* ap0 = A + (size_t)ar0 * lda + w * 8;
    const ushort* ap1 = A + (size_t)ar1 * lda + w * 8;
    const ushort* bp0 = W + (size_t)(n0 + lane) * K + w * 8;
    const ushort* bp1 = W + (size_t)(n0 + 64 + lane) * K + w * 8;

    const int l15 = lane & 15, l4 = lane >> 4;
    const int wm = w >> 1, wn = w & 1;
    f32x4 acc[4][4] = {};

    gload16(ap0, &As[0][w * 1024]);
    gload16(ap1, &As[0][w * 1024 + 512]);
    gload16(bp0, &Bs[0][w * 1024]);
    gload16(bp1, &Bs[0][w * 1024 + 512]);
    __syncthreads();

    const int NT = K / 32;
    int cur = 0;
    for (int t = 0; t < NT; ++t) {
        if (t + 1 < NT) {
            int ko = (t + 1) * 32;
            gload16(ap0 + ko, &As[cur ^ 1][w * 1024]);
            gload16(ap1 + ko, &As[cur ^ 1][w * 1024 + 512]);
            gload16(bp0 + ko, &Bs[cur ^ 1][w * 1024]);
            gload16(bp1 + ko, &Bs[cur ^ 1][w * 1024 + 512]);
        }
        bf16x8 af[4], bf_[4];
#pragma unroll
        for (int i = 0; i < 4; ++i) {
            af[i]  = *(const bf16x8*)&As[cur][l4 * 1024 + (wm * 64 + i * 16 + l15) * 8];
            bf_[i] = *(const bf16x8*)&Bs[cur][l4 * 1024 + (wn * 64 + i * 16 + l15) * 8];
        }
#pragma unroll
        for (int mi = 0; mi < 4; ++mi)
#pragma unroll
            for (int ni = 0; ni < 4; ++ni)
                acc[mi][ni] = __builtin_amdgcn_mfma_f32_16x16x32_bf16(af[mi], bf_[ni], acc[mi][ni], 0, 0, 0);
        __syncthreads();
        cur ^= 1;
    }
#pragma unroll
    for (int ni = 0; ni < 4; ++ni) {
        int col = n0 + wn * 64 + ni * 16 + l15;
        float bb = bi[col];
#pragma unroll
        for (int mi = 0; mi < 4; ++mi) {
            int ri = wm * 64 + mi * 16 + l4 * 4;
#pragma unroll
            for (int r = 0; r < 4; ++r) {
                float o = acc[mi][ni][r] + bb;
                if constexpr (SCAT) {
                    if (lb + ri + r < cnt)
                        C_[(size_t)toks[ri + r] * N + col] = f2bf(o);
                } else {
                    C_[(size_t)(row0 + ri + r) * N + col] = f2bf(o);
                }
            }
        }
    }
}

// ---------------- QKV GEMM: same loop, epilogue routes Q / K(head-major) / V(transposed) ----------------
__global__ __launch_bounds__(256) void k_qkv(const ushort* __restrict__ A,
                                             const ushort* __restrict__ Wb,
                                             const float* __restrict__ bias,
                                             ushort* __restrict__ Qb,
                                             ushort* __restrict__ Kb,
                                             ushort* __restrict__ Vb)
{
    const int N = 3 * DIMD, K = DIMD;
    __shared__ ushort As[2][4096];
    __shared__ ushort Bs[2][4096];
    const int tid = threadIdx.x, lane = tid & 63, w = tid >> 6;
    int bx, by;
    xcd_swizzle_cm(bx, by);
    const int n0 = bx * 128, row0 = by * 128;
    const ushort* ap0 = A + (size_t)(row0 + lane) * K + w * 8;
    const ushort* ap1 = A + (size_t)(row0 + 64 + lane) * K + w * 8;
    const ushort* bp0 = Wb + (size_t)(n0 + lane) * K + w * 8;
    const ushort* bp1 = Wb + (size_t)(n0 + 64 + lane) * K + w * 8;

    const int l15 = lane & 15, l4 = lane >> 4;
    const int wm = w >> 1, wn = w & 1;
    f32x4 acc[4][4] = {};

    gload16(ap0, &As[0][w * 1024]);
    gload16(ap1, &As[0][w * 1024 + 512]);
    gload16(bp0, &Bs[0][w * 1024]);
    gload16(bp1, &Bs[0][w * 1024 + 512]);
    __syncthreads();

    const int NT = K / 32;
    int cur = 0;
    for (int t = 0; t < NT; ++t) {
        if (t + 1 < NT) {
            int ko = (t + 1) * 32;
            gload16(ap0 + ko, &As[cur ^ 1][w * 1024]);
            gload16(ap1 + ko, &As[cur ^ 1][w * 1024 + 512]);
            gload16(bp0 + ko, &Bs[cur ^ 1][w * 1024]);
            gload16(bp1 + ko, &Bs[cur ^ 1][w * 1024 + 512]);
        }
        bf16x8 af[4], bf_[4];
#pragma unroll
        for (int i = 0; i < 4; ++i) {
            af[i]  = *(const bf16x8*)&As[cur][l4 * 1024 + (wm * 64 + i * 16 + l15) * 8];
            bf_[i] = *(const bf16x8*)&Bs[cur][l4 * 1024 + (wn * 64 + i * 16 + l15) * 8];
        }
#pragma unroll
        for (int mi = 0; mi < 4; ++mi)
#pragma unroll
            for (int ni = 0; ni < 4; ++ni)
                acc[mi][ni] = __builtin_amdgcn_mfma_f32_16x16x32_bf16(af[mi], bf_[ni], acc[mi][ni], 0, 0, 0);
        __syncthreads();
        cur ^= 1;
    }
#pragma unroll
    for (int ni = 0; ni < 4; ++ni) {
        int col = n0 + wn * 64 + ni * 16 + l15;
        float bb = bias[col];
#pragma unroll
        for (int mi = 0; mi < 4; ++mi) {
            int ri = wm * 64 + mi * 16 + l4 * 4;
#pragma unroll
            for (int r = 0; r < 4; ++r) {
                float o = acc[mi][ni][r] + bb;
                ushort v = f2bf(o);
                int row = row0 + ri + r;          // token
                int bq = row >> 9, sq = row & 511;
                if (col < DIMD) {
                    Qb[(size_t)row * DIMD + col] = v;
                } else if (col < 2 * DIMD) {
                    int hh = (col - DIMD) >> 6, dd = (col - DIMD) & 63;
                    Kb[(((size_t)(bq * NH + hh)) * SEQ + sq) * DHD + dd] = v;
                } else {
                    int hh = (col - 2 * DIMD) >> 6, dd = (col - 2 * DIMD) & 63;
                    Vb[(((size_t)(bq * NH + hh)) * DHD + dd) * SEQ + sq] = v;
                }
            }
        }
    }
}

// ---------------- W1 + GLU fused epilogue (R8 structure) ----------------
template<int MOE>
__global__ __launch_bounds__(256) void k_w1g(const ushort* __restrict__ A,
                                             const ushort* __restrict__ Wb,
                                             const float* __restrict__ bias,
                                             ushort* __restrict__ G,
                                             const int* __restrict__ perm,
                                             const int* __restrict__ offs,
                                             const int* __restrict__ blke,
                                             const int* __restrict__ blkb,
                                             const int* __restrict__ nblk)
{
    __shared__ ushort As[2][4096];
    __shared__ ushort Bs[2][8192];
    __shared__ int    toks[128];
    const int tid = threadIdx.x, lane = tid & 63, w = tid >> 6;
    int bx, by;
    xcd_swizzle_cm(bx, by);
    const int n0 = bx * 128, row0 = by * 128;
    const ushort* W = Wb;
    const float*  bi = bias;
    if constexpr (MOE) {
        if (by >= *nblk) return;
        int e = blke[by];
        W  += (size_t)e * FF2 * DIMD;
        bi += (size_t)e * FF2;
        int base = offs[e], cnt = offs[e + 1] - base, lb = blkb[by];
        if (tid < 128) { int rg = lb + tid; toks[tid] = perm[base + (rg < cnt ? rg : cnt - 1)]; }
        __syncthreads();
    }
    int ar0, ar1;
    if constexpr (MOE) { ar0 = toks[lane]; ar1 = toks[64 + lane]; }
    else               { ar0 = row0 + lane; ar1 = row0 + 64 + lane; }
    const ushort* ap0  = A + (size_t)ar0 * DIMD + w * 8;
    const ushort* ap1  = A + (size_t)ar1 * DIMD + w * 8;
    const ushort* bpa0 = W + (size_t)(n0 + lane) * DIMD + w * 8;
    const ushort* bpa1 = W + (size_t)(n0 + 64 + lane) * DIMD + w * 8;
    const ushort* bpb0 = W + (size_t)(FFD + n0 + lane) * DIMD + w * 8;
    const ushort* bpb1 = W + (size_t)(FFD + n0 + 64 + lane) * DIMD + w * 8;

    const int l15 = lane & 15, l4 = lane >> 4;
    const int wm = w >> 1, wn = w & 1;
    f32x4 accA[4][4] = {}, accB[4][4] = {};

    gload16(ap0,  &As[0][w * 1024]);
    gload16(ap1,  &As[0][w * 1024 + 512]);
    gload16(bpa0, &Bs[0][w * 2048]);
    gload16(bpa1, &Bs[0][w * 2048 + 512]);
    gload16(bpb0, &Bs[0][w * 2048 + 1024]);
    gload16(bpb1, &Bs[0][w * 2048 + 1536]);
    __syncthreads();

    const int NT = DIMD / 32;
    int cur = 0;
    for (int t = 0; t < NT; ++t) {
        if (t + 1 < NT) {
            int ko = (t + 1) * 32;
            gload16(ap0 + ko,  &As[cur ^ 1][w * 1024]);
            gload16(ap1 + ko,  &As[cur ^ 1][w * 1024 + 512]);
            gload16(bpa0 + ko, &Bs[cur ^ 1][w * 2048]);
            gload16(bpa1 + ko, &Bs[cur ^ 1][w * 2048 + 512]);
            gload16(bpb0 + ko, &Bs[cur ^ 1][w * 2048 + 1024]);
            gload16(bpb1 + ko, &Bs[cur ^ 1][w * 2048 + 1536]);
        }
        bf16x8 af[4], ba[4], bb[4];
#pragma unroll
        for (int i = 0; i < 4; ++i) {
            af[i] = *(const bf16x8*)&As[cur][l4 * 1024 + (wm * 64 + i * 16 + l15) * 8];
            ba[i] = *(const bf16x8*)&Bs[cur][l4 * 2048 + (wn * 64 + i * 16 + l15) * 8];
            bb[i] = *(const bf16x8*)&Bs[cur][l4 * 2048 + 1024 + (wn * 64 + i * 16 + l15) * 8];
        }
#pragma unroll
        for (int mi = 0; mi < 4; ++mi)
#pragma unroll
            for (int ni = 0; ni < 4; ++ni) {
                accA[mi][ni] = __builtin_amdgcn_mfma_f32_16x16x32_bf16(af[mi], ba[ni], accA[mi][ni], 0, 0, 0);
                accB[mi][ni] = __builtin_amdgcn_mfma_f32_16x16x32_bf16(af[mi], bb[ni], accB[mi][ni], 0, 0, 0);
            }
        __syncthreads();
        cur ^= 1;
    }
#pragma unroll
    for (int ni = 0; ni < 4; ++ni) {
        int col = n0 + wn * 64 + ni * 16 + l15;
        float fa = bi[col];
        float fb = bi[FFD + col];
#pragma unroll
        for (int mi = 0; mi < 4; ++mi) {
            int ri = wm * 64 + mi * 16 + l4 * 4;
#pragma unroll
            for (int r = 0; r < 4; ++r) {
                float a = accA[mi][ni][r] + fa;
                float b = accB[mi][ni][r] + fb;
                float g = a * (b / (1.f + __expf(-b)));
                G[(size_t)(row0 + ri + r) * FFD + col] = f2bf(g);
            }
        }
    }
}

// ---------------- MFMA flash attention (dense Q/K/V^T inputs) ----------------
__global__ __launch_bounds__(256) void k_attn(const ushort* __restrict__ Qb,
                                              const ushort* __restrict__ Kb,
                                              const ushort* __restrict__ Vb,
                                              ushort* __restrict__ out)
{
    __shared__ ushort Qs[64][72];
    __shared__ ushort Ks[64][72];
    __shared__ ushort Vt[64][72];
    __shared__ ushort Ps[4][16][72];
    const int bh = blockIdx.x;
    const int b = bh / NH, h = bh % NH;
    const int qt = blockIdx.y;
    const int tid = threadIdx.x, lane = tid & 63, w = tid >> 6;
    const int l15 = lane & 15, l4 = lane >> 4;
    const int t0 = b * SEQ + qt * 64;
    const ushort* kbase = Kb + (size_t)bh * SEQ * DHD;
    const ushort* vbase = Vb + (size_t)bh * DHD * SEQ;
    {
        int r = tid >> 3, c8 = (tid & 7) * 8;
#pragma unroll
        for (int p = 0; p < 2; ++p) {
            int rr = r + p * 32;
            *(uint4*)&Qs[rr][c8] = *(const uint4*)(Qb + (size_t)(t0 + rr) * DIMD + h * DHD + c8);
        }
    }
    __syncthreads();
    bf16x8 aq[2];
    aq[0] = *(const bf16x8*)&Qs[w*16 + l15][l4*8];
    aq[1] = *(const bf16x8*)&Qs[w*16 + l15][32 + l4*8];
    f32x4 o[4] = {};
    float m[4], lsum[4];
#pragma unroll
    for (int r = 0; r < 4; ++r) { m[r] = -3.0e38f; lsum[r] = 0.f; }
    for (int kt = 0; kt < SEQ; kt += 64) {
        __syncthreads();
        {
            // K tile: 64 keys x 64 dims, contiguous per key
            int r = tid >> 3, c8 = (tid & 7) * 8;
#pragma unroll
            for (int p = 0; p < 2; ++p) {
                int rr = r + p * 32;
                *(uint4*)&Ks[rr][c8] = *(const uint4*)(kbase + (size_t)(kt + rr) * DHD + c8);
            }
            // V^T tile: 64 dims x 64 keys, contiguous per dim
            int d = tid >> 2, c8v = (tid & 3) * 8;
            *(uint4*)&Vt[d][c8v]      = *(const uint4*)(vbase + (size_t)d * SEQ + kt + c8v);
            *(uint4*)&Vt[d][32 + c8v] = *(const uint4*)(vbase + (size_t)d * SEQ + kt + 32 + c8v);
        }
        __syncthreads();
        f32x4 s[4] = {};
#pragma unroll
        for (int kk = 0; kk < 2; ++kk)
#pragma unroll
            for (int ni = 0; ni < 4; ++ni) {
                bf16x8 bk = *(const bf16x8*)&Ks[ni*16 + l15][kk*32 + l4*8];
                s[ni] = __builtin_amdgcn_mfma_f32_16x16x32_bf16(aq[kk], bk, s[ni], 0, 0, 0);
            }
        float csc[4];
#pragma unroll
        for (int r = 0; r < 4; ++r) {
            float mx = -3.0e38f;
#pragma unroll
            for (int ni = 0; ni < 4; ++ni) { s[ni][r] *= 0.125f; mx = fmaxf(mx, s[ni][r]); }
            mx = fmaxf(mx, __shfl_xor(mx, 1));
            mx = fmaxf(mx, __shfl_xor(mx, 2));
            mx = fmaxf(mx, __shfl_xor(mx, 4));
            mx = fmaxf(mx, __shfl_xor(mx, 8));
            float nm = fmaxf(m[r], mx);
            float c = __expf(m[r] - nm);
            m[r] = nm;
            float ps = 0.f;
#pragma unroll
            for (int ni = 0; ni < 4; ++ni) { s[ni][r] = __expf(s[ni][r] - nm); ps += s[ni][r]; }
            ps += __shfl_xor(ps, 1);
            ps += __shfl_xor(ps, 2);
            ps += __shfl_xor(ps, 4);
            ps += __shfl_xor(ps, 8);
            lsum[r] = lsum[r] * c + ps;
            csc[r] = c;
#pragma unroll
            for (int ni = 0; ni < 4; ++ni)
                Ps[w][l4*4 + r][ni*16 + l15] = f2bf(s[ni][r]);
        }
#pragma unroll
        for (int di = 0; di < 4; ++di)
#pragma unroll
            for (int r = 0; r < 4; ++r) o[di][r] *= csc[r];
        bf16x8 ap[2];
        ap[0] = *(const bf16x8*)&Ps[w][l15][l4*8];
        ap[1] = *(const bf16x8*)&Ps[w][l15][32 + l4*8];
#pragma unroll
        for (int kk = 0; kk < 2; ++kk)
#pragma unroll
            for (int di = 0; di < 4; ++di) {
                bf16x8 bv = *(const bf16x8*)&Vt[di*16 + l15][kk*32 + l4*8];
                o[di] = __builtin_amdgcn_mfma_f32_16x16x32_bf16(ap[kk], bv, o[di], 0, 0, 0);
            }
    }
    float inv[4];
#pragma unroll
    for (int r = 0; r < 4; ++r) inv[r] = 1.f / lsum[r];
#pragma unroll
    for (int di = 0; di < 4; ++di)
#pragma unroll
        for (int r = 0; r < 4; ++r)
            out[(size_t)(t0 + w*16 + l4*4 + r) * DIMD + h * DHD + di*16 + l15] = f2bf(o[di][r] * inv[r]);
}

// ---------------- wave-per-row residual + LayerNorm -> X fp32 + Xb bf16 ----------------
__global__ __launch_bounds__(256) void k_ln(float* __restrict__ x, const ushort* __restrict__ fb,
                                            const float* __restrict__ g, const float* __restrict__ b,
                                            ushort* __restrict__ xb)
{
    const int t = blockIdx.x * 4 + (threadIdx.x >> 6);
    const int lane = threadIdx.x & 63;
    float* xr = x + (size_t)t * DIMD;
    const ushort* fr = fb + (size_t)t * DIMD;
    float v[12];
    float s = 0.f, s2 = 0.f;
#pragma unroll
    for (int j = 0; j < 12; ++j) {
        int d = lane + j * 64;
        float val = xr[d] + bf2f(fr[d]);
        v[j] = val; s += val; s2 = fmaf(val, val, s2);
    }
#pragma unroll
    for (int off = 1; off < 64; off <<= 1) {
        s  += __shfl_xor(s,  off);
        s2 += __shfl_xor(s2, off);
    }
    const float mean = s * (1.f / DIMD);
    const float var  = s2 * (1.f / DIMD) - mean * mean;
    const float rstd = rsqrtf(var + 1e-5f);
#pragma unroll
    for (int j = 0; j < 12; ++j) {
        int d = lane + j * 64;
        float o = (v[j] - mean) * rstd * g[d] + b[d];
        xr[d] = o;
        xb[(size_t)t * DIMD + d] = f2bf(o);
    }
}

// ---------------- MoE gating ----------------
__global__ __launch_bounds__(256) void k_gate(const float* __restrict__ x,
                                              const float* __restrict__ gAw, const float* __restrict__ gAb,
                                              const float* __restrict__ gBw, const float* __restrict__ gBb,
                                              float* __restrict__ sums, int* __restrict__ cnts,
                                              int* __restrict__ e_id)
{
    const int tid = threadIdx.x, lane = tid & 63, wid = tid >> 6;
    const int gw = blockIdx.x * 4 + wid;
    float wA0[12], wA1[12], wB0[12], wB1[12];
#pragma unroll
    for (int i = 0; i < 12; ++i) {
        int d = lane + i * 64;
        wA0[i] = gAw[d]; wA1[i] = gAw[DIMD + d];
        wB0[i] = gBw[d]; wB1[i] = gBw[DIMD + d];
    }
    const float bA0 = gAb[0], bA1 = gAb[1], bB0 = gBb[0], bB1 = gBb[1];
    float sA0 = 0.f, sA1 = 0.f, sB0 = 0.f, sB1 = 0.f;
    int cA1 = 0, cB1 = 0, cE0 = 0, cE1 = 0, cE2 = 0;
    for (int i = 0; i < 32; ++i) {
        int t = gw * 32 + i;
        const float* xr = x + (size_t)t * DIMD;
        float a0 = 0.f, a1 = 0.f, b0 = 0.f, b1 = 0.f;
#pragma unroll
        for (int j = 0; j < 12; ++j) {
            float v = xr[lane + j * 64];
            a0 = fmaf(v, wA0[j], a0); a1 = fmaf(v, wA1[j], a1);
            b0 = fmaf(v, wB0[j], b0); b1 = fmaf(v, wB1[j], b1);
        }
#pragma unroll
        for (int off = 1; off < 64; off <<= 1) {
            a0 += __shfl_xor(a0, off); a1 += __shfl_xor(a1, off);
            b0 += __shfl_xor(b0, off); b1 += __shfl_xor(b1, off);
        }
        a0 += bA0; a1 += bA1; b0 += bB0; b1 += bB1;
        int iA = (a1 > a0) ? 1 : 0;
        int iB = (b1 > b0) ? 1 : 0;
        float mA = fmaxf(a0, a1); float eA0 = __expf(a0 - mA), eA1 = __expf(a1 - mA);
        float dA = 1.f / (eA0 + eA1);
        float mB = fmaxf(b0, b1); float eB0 = __expf(b0 - mB), eB1 = __expf(b1 - mB);
        float dB = 1.f / (eB0 + eB1);
        sA0 += eA0 * dA; sA1 += eA1 * dA;
        sB0 += eB0 * dB; sB1 += eB1 * dB;
        cA1 += iA; cB1 += iB;
        int e = iA * 2 + iB;
        cE0 += (e == 0); cE1 += (e == 1); cE2 += (e == 2);
        if (lane == 0) e_id[t] = e;
    }
    __shared__ float fpart[4][4];
    __shared__ int   ipart[4][8];
    if (lane == 0) {
        fpart[wid][0] = sA0; fpart[wid][1] = sA1; fpart[wid][2] = sB0; fpart[wid][3] = sB1;
        ipart[wid][0] = 32 - cA1; ipart[wid][1] = cA1;
        ipart[wid][2] = 32 - cB1; ipart[wid][3] = cB1;
        ipart[wid][4] = cE0; ipart[wid][5] = cE1; ipart[wid][6] = cE2;
        ipart[wid][7] = 32 - cE0 - cE1 - cE2;
    }
    __syncthreads();
    if (tid < 4)  atomicAdd(sums + tid, fpart[0][tid] + fpart[1][tid] + fpart[2][tid] + fpart[3][tid]);
    else if (tid >= 64 && tid < 72) {
        int k = tid - 64;
        atomicAdd(cnts + k, ipart[0][k] + ipart[1][k] + ipart[2][k] + ipart[3][k]);
    }
}

__global__ void k_offsets(const int* __restrict__ cntE, int* __restrict__ offs, int* __restrict__ cursor,
                          int* __restrict__ nblk, int* __restrict__ blke, int* __restrict__ blkb)
{
    if (threadIdx.x == 0) {
        int a = 0, nb = 0;
        for (int e = 0; e < NEXP; ++e) {
            offs[e] = a; a += cntE[e]; cursor[e] = 0;
            int blocks = (cntE[e] + 127) >> 7;
            for (int b = 0; b < blocks; ++b) { blke[nb] = e; blkb[nb] = b * 128; ++nb; }
        }
        offs[NEXP] = a;
        *nblk = nb;
    }
}

__global__ __launch_bounds__(256) void k_scatter(const int* __restrict__ e_id, const int* __restrict__ offs,
                                                 int* __restrict__ cursor, int* __restrict__ perm)
{
    int t = blockIdx.x * 256 + threadIdx.x;
    int lane = threadIdx.x & 63;
    int e = e_id[t];
#pragma unroll
    for (int eo = 0; eo < NEXP; ++eo) {
        unsigned long long m = __ballot(e == eo);
        if (m == 0ULL) continue;
        int leader = __ffsll((long long)m) - 1;
        int base = 0;
        if (lane == leader) base = atomicAdd(cursor + eo, (int)__popcll(m));
        base = __shfl(base, leader);
        if (e == eo) {
            int lower = (int)__popcll(m & ((1ULL << lane) - 1ULL));
            perm[offs[eo] + base + lower] = t;
        }
    }
}

__global__ void k_aux(const float* __restrict__ sums, const int* __restrict__ cnts, float* __restrict__ aux_acc)
{
    if (threadIdx.x == 0) {
        const float invT2 = 1.f / ((float)TOK * (float)TOK);
        float aA = 2.f * (sums[0] * (float)cnts[0] + sums[1] * (float)cnts[1]) * invT2;
        float aB = 2.f * (sums[2] * (float)cnts[2] + sums[3] * (float)cnts[3]) * invT2;
        *aux_acc += aA + aB;
    }
}

// ---------------- classifier head ----------------
__global__ __launch_bounds__(256) void k_rep(const float* __restrict__ x, float* __restrict__ rep)
{
    int i = blockIdx.x * 256 + threadIdx.x;
    if (i >= NB_ * DIMD) return;
    int b = i / DIMD, d = i % DIMD;
    float s = 0.f;
    for (int q = 0; q < SEQ; ++q) s += x[((size_t)b * SEQ + q) * DIMD + d];
    rep[i] = s * (1.f / SEQ);
}

__global__ __launch_bounds__(256) void k_cls1(const float* __restrict__ rep, const float* __restrict__ cW1,
                                              const float* __restrict__ cB1, float* __restrict__ hcls)
{
    int w = blockIdx.x * 4 + (threadIdx.x >> 6);
    int lane = threadIdx.x & 63;
    if (w >= NB_ * DIMD) return;
    int b = w / DIMD, i = w % DIMD;
    float s = 0.f;
    for (int d = lane; d < DIMD; d += 64) s += rep[b * DIMD + d] * cW1[(size_t)i * DIMD + d];
    for (int off = 32; off > 0; off >>= 1) s += __shfl_down(s, off);
    if (lane == 0) hcls[w] = fmaxf(s + cB1[i], 0.f);
}

__global__ __launch_bounds__(256) void k_cls2(const float* __restrict__ hcls, const float* __restrict__ cW2,
                                              const float* __restrict__ cB2, float* __restrict__ out)
{
    int w = blockIdx.x * 4 + (threadIdx.x >> 6);
    int lane = threadIdx.x & 63;
    if (w >= NB_ * CCLS) return;
    int b = w / CCLS, c = w % CCLS;
    float s = 0.f;
    for (int d = lane; d < DIMD; d += 64) s += hcls[b * DIMD + d] * cW2[(size_t)c * DIMD + d];
    for (int off = 32; off > 0; off >>= 1) s += __shfl_down(s, off);
    if (lane == 0) out[w] = s + cB2[c];
}

__global__ void k_writeaux(const float* __restrict__ aux_acc, float* __restrict__ out)
{
    if (threadIdx.x == 0) out[NB_ * CCLS] = *aux_acc;
}

// ---------------- host launch ----------------
extern "C" void kernel_launch(void* const* d_in, const int* in_sizes, int n_in,
                              void* d_out, int out_size, void* d_ws, size_t ws_size,
                              hipStream_t stream)
{
    const int*   input_ids = (const int*)  d_in[0];
    const float* tok_emb   = (const float*)d_in[1];
    const float* pos_emb   = (const float*)d_in[2];
    const float* wqkv      = (const float*)d_in[3];
    const float* bqkv      = (const float*)d_in[4];
    const float* wo        = (const float*)d_in[5];
    const float* bo        = (const float*)d_in[6];
    const float* ln1g      = (const float*)d_in[7];
    const float* ln1b      = (const float*)d_in[8];
    const float* ln2g      = (const float*)d_in[9];
    const float* ln2b      = (const float*)d_in[10];
    const float* dW1       = (const float*)d_in[11];
    const float* dB1       = (const float*)d_in[12];
    const float* dW2       = (const float*)d_in[13];
    const float* dB2       = (const float*)d_in[14];
    const float* mW1       = (const float*)d_in[15];
    const float* mB1       = (const float*)d_in[16];
    const float* mW2       = (const float*)d_in[17];
    const float* mB2       = (const float*)d_in[18];
    const float* gAw       = (const float*)d_in[19];
    const float* gAb       = (const float*)d_in[20];
    const float* gBw       = (const float*)d_in[21];
    const float* gBb       = (const float*)d_in[22];
    const float* cW1       = (const float*)d_in[23];
    const float* cB1       = (const float*)d_in[24];
    const float* cW2       = (const float*)d_in[25];
    const float* cB2       = (const float*)d_in[26];

    float* out = (float*)d_out;
    float* ws  = (float*)d_ws;

    float*  X    = ws + OFF_X;
    ushort* XB   = (ushort*)(ws + OFF_XB);
    ushort* FB   = (ushort*)(ws + OFF_F);
    ushort* Qb   = (ushort*)(ws + OFF_SH);
    ushort* Kb   = Qb + (size_t)TOK * DIMD;
    ushort* Vb   = Kb + (size_t)TOK * DIMD;
    ushort* G    = (ushort*)(ws + OFF_SH + (size_t)TOK * 3 * DIMD / 2);
    ushort* Gg   = (ushort*)(ws + OFF_SH);     // FFN GLU'd activations (8704 x 3072 bf16)
    ushort* WQB  = (ushort*)(ws + OFF_WQ);
    ushort* WOB  = (ushort*)(ws + OFF_WOB);
    ushort* W1B  = (ushort*)(ws + OFF_W1B);
    ushort* W2B  = (ushort*)(ws + OFF_W2B);
    float*  REP  = ws + OFF_REP;
    float*  HCLS = ws + OFF_HCLS;
    float*  SUMS = ws + OFF_STAT;
    int*    INTB = (int*)(ws + OFF_INT);
    int*    CNTS = INTB;            // 8
    int*    OFFS = INTB + 8;        // 5
    int*    CURS = INTB + 13;       // 4
    int*    NBLK = INTB + 17;       // 1
    int*    BLKE = INTB + 18;       // 68
    int*    BLKB = INTB + 86;       // 68
    float*  AUXP = ws + OFF_AUX;
    int*    EID  = (int*)(ws + OFF_EID);
    int*    PERM = (int*)(ws + OFF_PERM);

    hipMemsetAsync(AUXP, 0, sizeof(float), stream);

    k_embed<<<dim3((TOK * DIMD / 4) / 256), 256, 0, stream>>>(input_ids, tok_emb, pos_emb, X, XB);

    int di = 0, mi = 0;
    for (int l = 0; l < 6; ++l) {
        const int moe = (l == 1 || l == 3 || l == 5);
        // --- per-layer weight conversion fp32->bf16 ---
        {
            int n8 = 3 * DIMD * DIMD / 8;
            k_cvt<<<dim3((n8 + 255) / 256), 256, 0, stream>>>(wqkv + (size_t)l * 3 * DIMD * DIMD, WQB, n8);
            n8 = DIMD * DIMD / 8;
            k_cvt<<<dim3((n8 + 255) / 256), 256, 0, stream>>>(wo + (size_t)l * DIMD * DIMD, WOB, n8);
            if (moe) {
                n8 = NEXP * FF2 * DIMD / 8;
                k_cvt<<<dim3((n8 + 255) / 256), 256, 0, stream>>>(mW1 + (size_t)mi * NEXP * FF2 * DIMD, W1B, n8);
                n8 = NEXP * DIMD * FFD / 8;
                k_cvt<<<dim3((n8 + 255) / 256), 256, 0, stream>>>(mW2 + (size_t)mi * NEXP * DIMD * FFD, W2B, n8);
            } else {
                n8 = FF2 * DIMD / 8;
                k_cvt<<<dim3((n8 + 255) / 256), 256, 0, stream>>>(dW1 + (size_t)di * FF2 * DIMD, W1B, n8);
                n8 = DIMD * FFD / 8;
                k_cvt<<<dim3((n8 + 255) / 256), 256, 0, stream>>>(dW2 + (size_t)di * DIMD * FFD, W2B, n8);
            }
        }
        // QKV projection with layout-routing epilogue
        k_qkv<<<dim3(3 * DIMD / 128, TOK / 128), 256, 0, stream>>>(
            XB, WQB, bqkv + (size_t)l * 3 * DIMD, Qb, Kb, Vb);
        // attention (dense Q/K/V^T)
        k_attn<<<dim3(NB_ * NH, SEQ / 64), 256, 0, stream>>>(Qb, Kb, Vb, G);
        // output projection (bf16 -> bf16 FB)
        k_mm<0,0><<<dim3(DIMD / 128, TOK / 128), 256, 0, stream>>>(
            G, WOB, bo + (size_t)l * DIMD, FB, DIMD, DIMD, DIMD,
            nullptr, nullptr, nullptr, nullptr, nullptr);
        k_ln<<<TOK / 4, 256, 0, stream>>>(X, FB, ln1g + (size_t)l * DIMD, ln1b + (size_t)l * DIMD, XB);

        if (moe) {
            hipMemsetAsync(SUMS, 0, 64, stream);
            k_gate<<<64, 256, 0, stream>>>(X,
                gAw + (size_t)mi * 2 * DIMD, gAb + (size_t)mi * 2,
                gBw + (size_t)mi * 2 * DIMD, gBb + (size_t)mi * 2,
                SUMS, CNTS, EID);
            k_offsets<<<1, 1, 0, stream>>>(CNTS + 4, OFFS, CURS, NBLK, BLKE, BLKB);
            k_scatter<<<TOK / 256, 256, 0, stream>>>(EID, OFFS, CURS, PERM);
            k_w1g<1><<<dim3(FFD / 128, 68), 256, 0, stream>>>(
                XB, W1B, mB1 + (size_t)mi * NEXP * FF2, Gg,
                PERM, OFFS, BLKE, BLKB, NBLK);
            k_mm<0,1><<<dim3(DIMD / 128, 68), 256, 0, stream>>>(
                Gg, W2B, mB2 + (size_t)mi * NEXP * DIMD, FB, DIMD, FFD, FFD,
                PERM, OFFS, BLKE, BLKB, NBLK);
            k_aux<<<1, 1, 0, stream>>>(SUMS, CNTS, AUXP);
            ++mi;
        } else {
            k_w1g<0><<<dim3(FFD / 128, TOK / 128), 256, 0, stream>>>(
                XB, W1B, dB1 + (size_t)di * FF2, Gg,
                nullptr, nullptr, nullptr, nullptr, nullptr);
            k_mm<0,0><<<dim3(DIMD / 128, TOK / 128), 256, 0, stream>>>(
                Gg, W2B, dB2 + (size_t)di * DIMD, FB, DIMD, FFD, FFD,
                nullptr, nullptr, nullptr, nullptr, nullptr);
            ++di;
        }
        k_ln<<<TOK / 4, 256, 0, stream>>>(X, FB, ln2g + (size_t)l * DIMD, ln2b + (size_t)l * DIMD, XB);
    }

    k_rep<<<dim3((NB_ * DIMD + 255) / 256), 256, 0, stream>>>(X, REP);
    k_cls1<<<dim3(NB_ * DIMD / 4), 256, 0, stream>>>(REP, cW1, cB1, HCLS);
    k_cls2<<<dim3((NB_ * CCLS + 3) / 4), 256, 0, stream>>>(HCLS, cW2, cB2, out);
    k_writeaux<<<1, 1, 0, stream>>>(AUXP, out);
}

// Round 15
// 2944.316 us; speedup vs baseline: 1.0398x; 1.0398x over previous
//
#include <hip/hip_runtime.h>
#include <cstddef>

#define TOK   8192
#define DIMD  768
#define NH    12
#define DHD   64
#define SEQ   512
#define NB_   16
#define FFD   3072
#define NEXP  4
#define CCLS  10
#define FF2   (2*FFD)

typedef short bf16x8 __attribute__((ext_vector_type(8)));
typedef float f32x4  __attribute__((ext_vector_type(4)));

// ---------------- workspace layout (float-slot units) ----------------
static const size_t OFF_X    = 0;                                   // TOK*D fp32
static const size_t OFF_XB   = OFF_X   + (size_t)TOK*DIMD;          // TOK*D bf16
static const size_t OFF_F    = OFF_XB  + (size_t)TOK*DIMD/2;        // TOK*D bf16 (residual branch)
static const size_t OFF_SH   = OFF_F   + (size_t)TOK*DIMD;          // shared: QKV+attnG | Gglu
static const size_t SH_FL    = (size_t)8704*FF2/2;
static const size_t OFF_WQ   = OFF_SH  + SH_FL;                     // qkv weights bf16
static const size_t OFF_WOB  = OFF_WQ  + (size_t)3*DIMD*DIMD/2;
static const size_t OFF_W1B  = OFF_WOB + (size_t)DIMD*DIMD/2;       // up to 4 experts
static const size_t OFF_W2B  = OFF_W1B + (size_t)NEXP*FF2*DIMD/2;
static const size_t OFF_REP  = OFF_W2B + (size_t)NEXP*DIMD*FFD/2;
static const size_t OFF_HCLS = OFF_REP + (size_t)NB_*DIMD;
static const size_t OFF_STAT = OFF_HCLS+ (size_t)NB_*DIMD;          // sums[4]+pad
static const size_t OFF_INT  = OFF_STAT+ 8;                         // 160 int slots
static const size_t OFF_AUX  = OFF_INT + 160;
static const size_t OFF_EID  = OFF_AUX + 1;                         // TOK ints
static const size_t OFF_PERM = OFF_EID + TOK;                       // TOK ints

__device__ __forceinline__ ushort f2bf(float f) {
    union { float f; unsigned u; } v; v.f = f;
    unsigned r = v.u + 0x7FFF + ((v.u >> 16) & 1);   // RNE
    return (ushort)(r >> 16);
}
__device__ __forceinline__ float bf2f(ushort u) {
    union { unsigned u; float f; } v; v.u = ((unsigned)u) << 16;
    return v.f;
}
__device__ __forceinline__ void gload16(const void* g, void* l) {
    __builtin_amdgcn_global_load_lds((const __attribute__((address_space(1))) void*)g,
                                     (__attribute__((address_space(3))) void*)l, 16, 0, 0);
}

// chunked-bijective XCD swizzle (column-major walk) — R10-proven
__device__ __forceinline__ void xcd_swizzle_cm(int& bx, int& by)
{
    int gx = gridDim.x, gy = gridDim.y;
    int bid = blockIdx.x * gy + blockIdx.y;
    int nwg = gx * gy;
    int q = nwg >> 3, r8 = nwg & 7;
    int xcd = bid & 7, loc = bid >> 3;
    int lbid = (xcd < r8 ? xcd * (q + 1) : r8 * (q + 1) + (xcd - r8) * q) + loc;
    bx = lbid / gy;
    by = lbid % gy;
}

// ---------------- segmented weight fp32 -> bf16 conversion (one launch per layer) ----------------
__global__ __launch_bounds__(256) void k_cvt4(const float* __restrict__ s0, ushort* __restrict__ d0, int n0,
                                              const float* __restrict__ s1, ushort* __restrict__ d1, int n1,
                                              const float* __restrict__ s2, ushort* __restrict__ d2, int n2,
                                              const float* __restrict__ s3, ushort* __restrict__ d3, int n3)
{
    int i = blockIdx.x * 256 + threadIdx.x;
    const float* s; ushort* d; int j = i;
    if (j < n0) { s = s0; d = d0; }
    else {
        j -= n0;
        if (j < n1) { s = s1; d = d1; }
        else {
            j -= n1;
            if (j < n2) { s = s2; d = d2; }
            else {
                j -= n2;
                if (j >= n3) return;
                s = s3; d = d3;
            }
        }
    }
    float4 x0 = ((const float4*)s)[j * 2];
    float4 x1 = ((const float4*)s)[j * 2 + 1];
    ushort r[8] = { f2bf(x0.x), f2bf(x0.y), f2bf(x0.z), f2bf(x0.w),
                    f2bf(x1.x), f2bf(x1.y), f2bf(x1.z), f2bf(x1.w) };
    ((uint4*)d)[j] = *(uint4*)r;
}

// ---------------- embedding: X fp32 + Xb bf16 ----------------
__global__ __launch_bounds__(256) void k_embed(const int* __restrict__ ids,
                                               const float* __restrict__ te,
                                               const float* __restrict__ pe,
                                               float* __restrict__ x,
                                               ushort* __restrict__ xb)
{
    int i = blockIdx.x * 256 + threadIdx.x;
    const int nd4 = DIMD / 4;
    if (i >= TOK * nd4) return;
    int t = i / nd4, d4 = i % nd4;
    int s = t % SEQ;
    int id = ids[t];
    float4 a = ((const float4*)(te + (size_t)id * DIMD))[d4];
    float4 b = ((const float4*)(pe + (size_t)s  * DIMD))[d4];
    float4 o; o.x = a.x + b.x; o.y = a.y + b.y; o.z = a.z + b.z; o.w = a.w + b.w;
    ((float4*)(x + (size_t)t * DIMD))[d4] = o;
    ushort4 ob = make_ushort4(f2bf(o.x), f2bf(o.y), f2bf(o.z), f2bf(o.w));
    *(ushort4*)(xb + (size_t)t * DIMD + d4 * 4) = ob;
}

// ---------------- 128x128 MFMA GEMM (R8/R10-proven 2-barrier loop) ----------------
// slot-major LDS, global_load_lds(16B), double-buffered, one barrier/K-step.
// GATHER: A rows via toks. SCAT: C bf16 scattered to F[token].
template<int GATHER, int SCAT>
__global__ __launch_bounds__(256) void k_mm(const ushort* __restrict__ A,
                                            const ushort* __restrict__ Wb,
                                            const float* __restrict__ bias,
                                            ushort* __restrict__ C_,
                                            int N, int K, int lda,
                                            const int* __restrict__ perm,
                                            const int* __restrict__ offs,
                                            const int* __restrict__ blke,
                                            const int* __restrict__ blkb,
                                            const int* __restrict__ nblk)
{
    constexpr int MOE = GATHER || SCAT;
    __shared__ ushort As[2][4096];
    __shared__ ushort Bs[2][4096];
    __shared__ int    toks[128];
    const int tid = threadIdx.x, lane = tid & 63, w = tid >> 6;
    int bx, by;
    xcd_swizzle_cm(bx, by);
    const int n0 = bx * 128, row0 = by * 128;
    const ushort* W = Wb;
    const float*  bi = bias;
    int lb = 0, cnt = 1 << 30;
    if constexpr (MOE) {
        if (by >= *nblk) return;
        int e = blke[by];
        lb = blkb[by];
        int base = offs[e];
        cnt = offs[e + 1] - base;
        W  += (size_t)e * N * K;
        bi += (size_t)e * N;
        if (tid < 128) { int rg = lb + tid; toks[tid] = perm[base + (rg < cnt ? rg : cnt - 1)]; }
        __syncthreads();
    }
    int ar0, ar1;
    if constexpr (GATHER) { ar0 = toks[lane]; ar1 = toks[64 + lane]; }
    else                  { ar0 = row0 + lane; ar1 = row0 + 64 + lane; }
    const ushort* ap0 = A + (size_t)ar0 * lda + w * 8;
    const ushort* ap1 = A + (size_t)ar1 * lda + w * 8;
    const ushort* bp0 = W + (size_t)(n0 + lane) * K + w * 8;
    const ushort* bp1 = W + (size_t)(n0 + 64 + lane) * K + w * 8;

    const int l15 = lane & 15, l4 = lane >> 4;
    const int wm = w >> 1, wn = w & 1;
    f32x4 acc[4][4] = {};

    gload16(ap0, &As[0][w * 1024]);
    gload16(ap1, &As[0][w * 1024 + 512]);
    gload16(bp0, &Bs[0][w * 1024]);
    gload16(bp1, &Bs[0][w * 1024 + 512]);
    __syncthreads();

    const int NT = K / 32;
    int cur = 0;
    for (int t = 0; t < NT; ++t) {
        if (t + 1 < NT) {
            int ko = (t + 1) * 32;
            gload16(ap0 + ko, &As[cur ^ 1][w * 1024]);
            gload16(ap1 + ko, &As[cur ^ 1][w * 1024 + 512]);
            gload16(bp0 + ko, &Bs[cur ^ 1][w * 1024]);
            gload16(bp1 + ko, &Bs[cur ^ 1][w * 1024 + 512]);
        }
        bf16x8 af[4], bf_[4];
#pragma unroll
        for (int i = 0; i < 4; ++i) {
            af[i]  = *(const bf16x8*)&As[cur][l4 * 1024 + (wm * 64 + i * 16 + l15) * 8];
            bf_[i] = *(const bf16x8*)&Bs[cur][l4 * 1024 + (wn * 64 + i * 16 + l15) * 8];
        }
#pragma unroll
        for (int mi = 0; mi < 4; ++mi)
#pragma unroll
            for (int ni = 0; ni < 4; ++ni)
                acc[mi][ni] = __builtin_amdgcn_mfma_f32_16x16x32_bf16(af[mi], bf_[ni], acc[mi][ni], 0, 0, 0);
        __syncthreads();
        cur ^= 1;
    }
#pragma unroll
    for (int ni = 0; ni < 4; ++ni) {
        int col = n0 + wn * 64 + ni * 16 + l15;
        float bb = bi[col];
#pragma unroll
        for (int mi = 0; mi < 4; ++mi) {
            int ri = wm * 64 + mi * 16 + l4 * 4;
#pragma unroll
            for (int r = 0; r < 4; ++r) {
                float o = acc[mi][ni][r] + bb;
                if constexpr (SCAT) {
                    if (lb + ri + r < cnt)
                        C_[(size_t)toks[ri + r] * N + col] = f2bf(o);
                } else {
                    C_[(size_t)(row0 + ri + r) * N + col] = f2bf(o);
                }
            }
        }
    }
}

// ---------------- W1 + GLU fused epilogue (R8 structure) ----------------
template<int MOE>
__global__ __launch_bounds__(256) void k_w1g(const ushort* __restrict__ A,
                                             const ushort* __restrict__ Wb,
                                             const float* __restrict__ bias,
                                             ushort* __restrict__ G,
                                             const int* __restrict__ perm,
                                             const int* __restrict__ offs,
                                             const int* __restrict__ blke,
                                             const int* __restrict__ blkb,
                                             const int* __restrict__ nblk)
{
    __shared__ ushort As[2][4096];
    __shared__ ushort Bs[2][8192];
    __shared__ int    toks[128];
    const int tid = threadIdx.x, lane = tid & 63, w = tid >> 6;
    int bx, by;
    xcd_swizzle_cm(bx, by);
    const int n0 = bx * 128, row0 = by * 128;
    const ushort* W = Wb;
    const float*  bi = bias;
    if constexpr (MOE) {
        if (by >= *nblk) return;
        int e = blke[by];
        W  += (size_t)e * FF2 * DIMD;
        bi += (size_t)e * FF2;
        int base = offs[e], cnt = offs[e + 1] - base, lb = blkb[by];
        if (tid < 128) { int rg = lb + tid; toks[tid] = perm[base + (rg < cnt ? rg : cnt - 1)]; }
        __syncthreads();
    }
    int ar0, ar1;
    if constexpr (MOE) { ar0 = toks[lane]; ar1 = toks[64 + lane]; }
    else               { ar0 = row0 + lane; ar1 = row0 + 64 + lane; }
    const ushort* ap0  = A + (size_t)ar0 * DIMD + w * 8;
    const ushort* ap1  = A + (size_t)ar1 * DIMD + w * 8;
    const ushort* bpa0 = W + (size_t)(n0 + lane) * DIMD + w * 8;
    const ushort* bpa1 = W + (size_t)(n0 + 64 + lane) * DIMD + w * 8;
    const ushort* bpb0 = W + (size_t)(FFD + n0 + lane) * DIMD + w * 8;
    const ushort* bpb1 = W + (size_t)(FFD + n0 + 64 + lane) * DIMD + w * 8;

    const int l15 = lane & 15, l4 = lane >> 4;
    const int wm = w >> 1, wn = w & 1;
    f32x4 accA[4][4] = {}, accB[4][4] = {};

    gload16(ap0,  &As[0][w * 1024]);
    gload16(ap1,  &As[0][w * 1024 + 512]);
    gload16(bpa0, &Bs[0][w * 2048]);
    gload16(bpa1, &Bs[0][w * 2048 + 512]);
    gload16(bpb0, &Bs[0][w * 2048 + 1024]);
    gload16(bpb1, &Bs[0][w * 2048 + 1536]);
    __syncthreads();

    const int NT = DIMD / 32;
    int cur = 0;
    for (int t = 0; t < NT; ++t) {
        if (t + 1 < NT) {
            int ko = (t + 1) * 32;
            gload16(ap0 + ko,  &As[cur ^ 1][w * 1024]);
            gload16(ap1 + ko,  &As[cur ^ 1][w * 1024 + 512]);
            gload16(bpa0 + ko, &Bs[cur ^ 1][w * 2048]);
            gload16(bpa1 + ko, &Bs[cur ^ 1][w * 2048 + 512]);
            gload16(bpb0 + ko, &Bs[cur ^ 1][w * 2048 + 1024]);
            gload16(bpb1 + ko, &Bs[cur ^ 1][w * 2048 + 1536]);
        }
        bf16x8 af[4], ba[4], bb[4];
#pragma unroll
        for (int i = 0; i < 4; ++i) {
            af[i] = *(const bf16x8*)&As[cur][l4 * 1024 + (wm * 64 + i * 16 + l15) * 8];
            ba[i] = *(const bf16x8*)&Bs[cur][l4 * 2048 + (wn * 64 + i * 16 + l15) * 8];
            bb[i] = *(const bf16x8*)&Bs[cur][l4 * 2048 + 1024 + (wn * 64 + i * 16 + l15) * 8];
        }
#pragma unroll
        for (int mi = 0; mi < 4; ++mi)
#pragma unroll
            for (int ni = 0; ni < 4; ++ni) {
                accA[mi][ni] = __builtin_amdgcn_mfma_f32_16x16x32_bf16(af[mi], ba[ni], accA[mi][ni], 0, 0, 0);
                accB[mi][ni] = __builtin_amdgcn_mfma_f32_16x16x32_bf16(af[mi], bb[ni], accB[mi][ni], 0, 0, 0);
            }
        __syncthreads();
        cur ^= 1;
    }
#pragma unroll
    for (int ni = 0; ni < 4; ++ni) {
        int col = n0 + wn * 64 + ni * 16 + l15;
        float fa = bi[col];
        float fb = bi[FFD + col];
#pragma unroll
        for (int mi = 0; mi < 4; ++mi) {
            int ri = wm * 64 + mi * 16 + l4 * 4;
#pragma unroll
            for (int r = 0; r < 4; ++r) {
                float a = accA[mi][ni][r] + fa;
                float b = accB[mi][ni][r] + fb;
                float g = a * (b / (1.f + __expf(-b)));
                G[(size_t)(row0 + ri + r) * FFD + col] = f2bf(g);
            }
        }
    }
}

// ---------------- MFMA flash attention (packed QKV, R8-proven) ----------------
__global__ __launch_bounds__(256) void k_attn(const ushort* __restrict__ qkv, ushort* __restrict__ out)
{
    __shared__ ushort Qs[64][72];
    __shared__ ushort Ks[64][72];
    __shared__ ushort Vt[64][72];
    __shared__ ushort Ps[4][16][72];
    const int bh = blockIdx.x;
    const int b = bh / NH, h = bh % NH;
    const int qt = blockIdx.y;
    const int tid = threadIdx.x, lane = tid & 63, w = tid >> 6;
    const int l15 = lane & 15, l4 = lane >> 4;
    const int t0 = b * SEQ + qt * 64;
    {
        int r = tid >> 3, c8 = (tid & 7) * 8;
#pragma unroll
        for (int p = 0; p < 2; ++p) {
            int rr = r + p * 32;
            *(uint4*)&Qs[rr][c8] = *(const uint4*)(qkv + (size_t)(t0 + rr) * 3 * DIMD + h * DHD + c8);
        }
    }
    __syncthreads();
    bf16x8 aq[2];
    aq[0] = *(const bf16x8*)&Qs[w*16 + l15][l4*8];
    aq[1] = *(const bf16x8*)&Qs[w*16 + l15][32 + l4*8];
    f32x4 o[4] = {};
    float m[4], lsum[4];
#pragma unroll
    for (int r = 0; r < 4; ++r) { m[r] = -3.0e38f; lsum[r] = 0.f; }
    for (int kt = 0; kt < SEQ; kt += 64) {
        __syncthreads();
        {
            int r = tid >> 3, c8 = (tid & 7) * 8;
#pragma unroll
            for (int p = 0; p < 2; ++p) {
                int rr = r + p * 32;
                const ushort* kp = qkv + (size_t)(b * SEQ + kt + rr) * 3 * DIMD + DIMD + h * DHD;
                *(uint4*)&Ks[rr][c8] = *(const uint4*)(kp + c8);
                uint4 vv = *(const uint4*)(kp + DIMD + c8);
                const ushort* vs = (const ushort*)&vv;
#pragma unroll
                for (int j = 0; j < 8; ++j) Vt[c8 + j][rr] = vs[j];
            }
        }
        __syncthreads();
        f32x4 s[4] = {};
#pragma unroll
        for (int kk = 0; kk < 2; ++kk)
#pragma unroll
            for (int ni = 0; ni < 4; ++ni) {
                bf16x8 bk = *(const bf16x8*)&Ks[ni*16 + l15][kk*32 + l4*8];
                s[ni] = __builtin_amdgcn_mfma_f32_16x16x32_bf16(aq[kk], bk, s[ni], 0, 0, 0);
            }
        float csc[4];
#pragma unroll
        for (int r = 0; r < 4; ++r) {
            float mx = -3.0e38f;
#pragma unroll
            for (int ni = 0; ni < 4; ++ni) { s[ni][r] *= 0.125f; mx = fmaxf(mx, s[ni][r]); }
            mx = fmaxf(mx, __shfl_xor(mx, 1));
            mx = fmaxf(mx, __shfl_xor(mx, 2));
            mx = fmaxf(mx, __shfl_xor(mx, 4));
            mx = fmaxf(mx, __shfl_xor(mx, 8));
            float nm = fmaxf(m[r], mx);
            float c = __expf(m[r] - nm);
            m[r] = nm;
            float ps = 0.f;
#pragma unroll
            for (int ni = 0; ni < 4; ++ni) { s[ni][r] = __expf(s[ni][r] - nm); ps += s[ni][r]; }
            ps += __shfl_xor(ps, 1);
            ps += __shfl_xor(ps, 2);
            ps += __shfl_xor(ps, 4);
            ps += __shfl_xor(ps, 8);
            lsum[r] = lsum[r] * c + ps;
            csc[r] = c;
#pragma unroll
            for (int ni = 0; ni < 4; ++ni)
                Ps[w][l4*4 + r][ni*16 + l15] = f2bf(s[ni][r]);
        }
#pragma unroll
        for (int di = 0; di < 4; ++di)
#pragma unroll
            for (int r = 0; r < 4; ++r) o[di][r] *= csc[r];
        bf16x8 ap[2];
        ap[0] = *(const bf16x8*)&Ps[w][l15][l4*8];
        ap[1] = *(const bf16x8*)&Ps[w][l15][32 + l4*8];
#pragma unroll
        for (int kk = 0; kk < 2; ++kk)
#pragma unroll
            for (int di = 0; di < 4; ++di) {
                bf16x8 bv = *(const bf16x8*)&Vt[di*16 + l15][kk*32 + l4*8];
                o[di] = __builtin_amdgcn_mfma_f32_16x16x32_bf16(ap[kk], bv, o[di], 0, 0, 0);
            }
    }
    float inv[4];
#pragma unroll
    for (int r = 0; r < 4; ++r) inv[r] = 1.f / lsum[r];
#pragma unroll
    for (int di = 0; di < 4; ++di)
#pragma unroll
        for (int r = 0; r < 4; ++r)
            out[(size_t)(t0 + w*16 + l4*4 + r) * DIMD + h * DHD + di*16 + l15] = f2bf(o[di][r] * inv[r]);
}

// ---------------- wave-per-row residual + LayerNorm -> X fp32 + Xb bf16 ----------------
__global__ __launch_bounds__(256) void k_ln(float* __restrict__ x, const ushort* __restrict__ fb,
                                            const float* __restrict__ g, const float* __restrict__ b,
                                            ushort* __restrict__ xb)
{
    const int t = blockIdx.x * 4 + (threadIdx.x >> 6);
    const int lane = threadIdx.x & 63;
    float* xr = x + (size_t)t * DIMD;
    const ushort* fr = fb + (size_t)t * DIMD;
    float v[12];
    float s = 0.f, s2 = 0.f;
#pragma unroll
    for (int j = 0; j < 12; ++j) {
        int d = lane + j * 64;
        float val = xr[d] + bf2f(fr[d]);
        v[j] = val; s += val; s2 = fmaf(val, val, s2);
    }
#pragma unroll
    for (int off = 1; off < 64; off <<= 1) {
        s  += __shfl_xor(s,  off);
        s2 += __shfl_xor(s2, off);
    }
    const float mean = s * (1.f / DIMD);
    const float var  = s2 * (1.f / DIMD) - mean * mean;
    const float rstd = rsqrtf(var + 1e-5f);
#pragma unroll
    for (int j = 0; j < 12; ++j) {
        int d = lane + j * 64;
        float o = (v[j] - mean) * rstd * g[d] + b[d];
        xr[d] = o;
        xb[(size_t)t * DIMD + d] = f2bf(o);
    }
}

// ---------------- MoE gating ----------------
__global__ __launch_bounds__(256) void k_gate(const float* __restrict__ x,
                                              const float* __restrict__ gAw, const float* __restrict__ gAb,
                                              const float* __restrict__ gBw, const float* __restrict__ gBb,
                                              float* __restrict__ sums, int* __restrict__ cnts,
                                              int* __restrict__ e_id)
{
    const int tid = threadIdx.x, lane = tid & 63, wid = tid >> 6;
    const int gw = blockIdx.x * 4 + wid;
    float wA0[12], wA1[12], wB0[12], wB1[12];
#pragma unroll
    for (int i = 0; i < 12; ++i) {
        int d = lane + i * 64;
        wA0[i] = gAw[d]; wA1[i] = gAw[DIMD + d];
        wB0[i] = gBw[d]; wB1[i] = gBw[DIMD + d];
    }
    const float bA0 = gAb[0], bA1 = gAb[1], bB0 = gBb[0], bB1 = gBb[1];
    float sA0 = 0.f, sA1 = 0.f, sB0 = 0.f, sB1 = 0.f;
    int cA1 = 0, cB1 = 0, cE0 = 0, cE1 = 0, cE2 = 0;
    for (int i = 0; i < 32; ++i) {
        int t = gw * 32 + i;
        const float* xr = x + (size_t)t * DIMD;
        float a0 = 0.f, a1 = 0.f, b0 = 0.f, b1 = 0.f;
#pragma unroll
        for (int j = 0; j < 12; ++j) {
            float v = xr[lane + j * 64];
            a0 = fmaf(v, wA0[j], a0); a1 = fmaf(v, wA1[j], a1);
            b0 = fmaf(v, wB0[j], b0); b1 = fmaf(v, wB1[j], b1);
        }
#pragma unroll
        for (int off = 1; off < 64; off <<= 1) {
            a0 += __shfl_xor(a0, off); a1 += __shfl_xor(a1, off);
            b0 += __shfl_xor(b0, off); b1 += __shfl_xor(b1, off);
        }
        a0 += bA0; a1 += bA1; b0 += bB0; b1 += bB1;
        int iA = (a1 > a0) ? 1 : 0;
        int iB = (b1 > b0) ? 1 : 0;
        float mA = fmaxf(a0, a1); float eA0 = __expf(a0 - mA), eA1 = __expf(a1 - mA);
        float dA = 1.f / (eA0 + eA1);
        float mB = fmaxf(b0, b1); float eB0 = __expf(b0 - mB), eB1 = __expf(b1 - mB);
        float dB = 1.f / (eB0 + eB1);
        sA0 += eA0 * dA; sA1 += eA1 * dA;
        sB0 += eB0 * dB; sB1 += eB1 * dB;
        cA1 += iA; cB1 += iB;
        int e = iA * 2 + iB;
        cE0 += (e == 0); cE1 += (e == 1); cE2 += (e == 2);
        if (lane == 0) e_id[t] = e;
    }
    __shared__ float fpart[4][4];
    __shared__ int   ipart[4][8];
    if (lane == 0) {
        fpart[wid][0] = sA0; fpart[wid][1] = sA1; fpart[wid][2] = sB0; fpart[wid][3] = sB1;
        ipart[wid][0] = 32 - cA1; ipart[wid][1] = cA1;
        ipart[wid][2] = 32 - cB1; ipart[wid][3] = cB1;
        ipart[wid][4] = cE0; ipart[wid][5] = cE1; ipart[wid][6] = cE2;
        ipart[wid][7] = 32 - cE0 - cE1 - cE2;
    }
    __syncthreads();
    if (tid < 4)  atomicAdd(sums + tid, fpart[0][tid] + fpart[1][tid] + fpart[2][tid] + fpart[3][tid]);
    else if (tid >= 64 && tid < 72) {
        int k = tid - 64;
        atomicAdd(cnts + k, ipart[0][k] + ipart[1][k] + ipart[2][k] + ipart[3][k]);
    }
}

__global__ void k_offsets(const int* __restrict__ cntE, int* __restrict__ offs, int* __restrict__ cursor,
                          int* __restrict__ nblk, int* __restrict__ blke, int* __restrict__ blkb)
{
    if (threadIdx.x == 0) {
        int a = 0, nb = 0;
        for (int e = 0; e < NEXP; ++e) {
            offs[e] = a; a += cntE[e]; cursor[e] = 0;
            int blocks = (cntE[e] + 127) >> 7;
            for (int b = 0; b < blocks; ++b) { blke[nb] = e; blkb[nb] = b * 128; ++nb; }
        }
        offs[NEXP] = a;
        *nblk = nb;
    }
}

__global__ __launch_bounds__(256) void k_scatter(const int* __restrict__ e_id, const int* __restrict__ offs,
                                                 int* __restrict__ cursor, int* __restrict__ perm)
{
    int t = blockIdx.x * 256 + threadIdx.x;
    int lane = threadIdx.x & 63;
    int e = e_id[t];
#pragma unroll
    for (int eo = 0; eo < NEXP; ++eo) {
        unsigned long long m = __ballot(e == eo);
        if (m == 0ULL) continue;
        int leader = __ffsll((long long)m) - 1;
        int base = 0;
        if (lane == leader) base = atomicAdd(cursor + eo, (int)__popcll(m));
        base = __shfl(base, leader);
        if (e == eo) {
            int lower = (int)__popcll(m & ((1ULL << lane) - 1ULL));
            perm[offs[eo] + base + lower] = t;
        }
    }
}

__global__ void k_aux(const float* __restrict__ sums, const int* __restrict__ cnts, float* __restrict__ aux_acc)
{
    if (threadIdx.x == 0) {
        const float invT2 = 1.f / ((float)TOK * (float)TOK);
        float aA = 2.f * (sums[0] * (float)cnts[0] + sums[1] * (float)cnts[1]) * invT2;
        float aB = 2.f * (sums[2] * (float)cnts[2] + sums[3] * (float)cnts[3]) * invT2;
        *aux_acc += aA + aB;
    }
}

// ---------------- classifier head ----------------
__global__ __launch_bounds__(256) void k_rep(const float* __restrict__ x, float* __restrict__ rep)
{
    int i = blockIdx.x * 256 + threadIdx.x;
    if (i >= NB_ * DIMD) return;
    int b = i / DIMD, d = i % DIMD;
    float s = 0.f;
    for (int q = 0; q < SEQ; ++q) s += x[((size_t)b * SEQ + q) * DIMD + d];
    rep[i] = s * (1.f / SEQ);
}

__global__ __launch_bounds__(256) void k_cls1(const float* __restrict__ rep, const float* __restrict__ cW1,
                                              const float* __restrict__ cB1, float* __restrict__ hcls)
{
    int w = blockIdx.x * 4 + (threadIdx.x >> 6);
    int lane = threadIdx.x & 63;
    if (w >= NB_ * DIMD) return;
    int b = w / DIMD, i = w % DIMD;
    float s = 0.f;
    for (int d = lane; d < DIMD; d += 64) s += rep[b * DIMD + d] * cW1[(size_t)i * DIMD + d];
    for (int off = 32; off > 0; off >>= 1) s += __shfl_down(s, off);
    if (lane == 0) hcls[w] = fmaxf(s + cB1[i], 0.f);
}

__global__ __launch_bounds__(256) void k_cls2(const float* __restrict__ hcls, const float* __restrict__ cW2,
                                              const float* __restrict__ cB2, float* __restrict__ out)
{
    int w = blockIdx.x * 4 + (threadIdx.x >> 6);
    int lane = threadIdx.x & 63;
    if (w >= NB_ * CCLS) return;
    int b = w / CCLS, c = w % CCLS;
    float s = 0.f;
    for (int d = lane; d < DIMD; d += 64) s += hcls[b * DIMD + d] * cW2[(size_t)c * DIMD + d];
    for (int off = 32; off > 0; off >>= 1) s += __shfl_down(s, off);
    if (lane == 0) out[w] = s + cB2[c];
}

__global__ void k_writeaux(const float* __restrict__ aux_acc, float* __restrict__ out)
{
    if (threadIdx.x == 0) out[NB_ * CCLS] = *aux_acc;
}

// ---------------- host launch ----------------
extern "C" void kernel_launch(void* const* d_in, const int* in_sizes, int n_in,
                              void* d_out, int out_size, void* d_ws, size_t ws_size,
                              hipStream_t stream)
{
    const int*   input_ids = (const int*)  d_in[0];
    const float* tok_emb   = (const float*)d_in[1];
    const float* pos_emb   = (const float*)d_in[2];
    const float* wqkv      = (const float*)d_in[3];
    const float* bqkv      = (const float*)d_in[4];
    const float* wo        = (const float*)d_in[5];
    const float* bo        = (const float*)d_in[6];
    const float* ln1g      = (const float*)d_in[7];
    const float* ln1b      = (const float*)d_in[8];
    const float* ln2g      = (const float*)d_in[9];
    const float* ln2b      = (const float*)d_in[10];
    const float* dW1       = (const float*)d_in[11];
    const float* dB1       = (const float*)d_in[12];
    const float* dW2       = (const float*)d_in[13];
    const float* dB2       = (const float*)d_in[14];
    const float* mW1       = (const float*)d_in[15];
    const float* mB1       = (const float*)d_in[16];
    const float* mW2       = (const float*)d_in[17];
    const float* mB2       = (const float*)d_in[18];
    const float* gAw       = (const float*)d_in[19];
    const float* gAb       = (const float*)d_in[20];
    const float* gBw       = (const float*)d_in[21];
    const float* gBb       = (const float*)d_in[22];
    const float* cW1       = (const float*)d_in[23];
    const float* cB1       = (const float*)d_in[24];
    const float* cW2       = (const float*)d_in[25];
    const float* cB2       = (const float*)d_in[26];

    float* out = (float*)d_out;
    float* ws  = (float*)d_ws;

    float*  X    = ws + OFF_X;
    ushort* XB   = (ushort*)(ws + OFF_XB);
    ushort* FB   = (ushort*)(ws + OFF_F);
    ushort* QKV  = (ushort*)(ws + OFF_SH);
    ushort* G    = (ushort*)(ws + OFF_SH + (size_t)TOK * 3 * DIMD / 2);
    ushort* Gg   = (ushort*)(ws + OFF_SH);     // FFN GLU'd activations (8704 x 3072 bf16)
    ushort* WQB  = (ushort*)(ws + OFF_WQ);
    ushort* WOB  = (ushort*)(ws + OFF_WOB);
    ushort* W1B  = (ushort*)(ws + OFF_W1B);
    ushort* W2B  = (ushort*)(ws + OFF_W2B);
    float*  REP  = ws + OFF_REP;
    float*  HCLS = ws + OFF_HCLS;
    float*  SUMS = ws + OFF_STAT;
    int*    INTB = (int*)(ws + OFF_INT);
    int*    CNTS = INTB;            // 8
    int*    OFFS = INTB + 8;        // 5
    int*    CURS = INTB + 13;       // 4
    int*    NBLK = INTB + 17;       // 1
    int*    BLKE = INTB + 18;       // 68
    int*    BLKB = INTB + 86;       // 68
    float*  AUXP = ws + OFF_AUX;
    int*    EID  = (int*)(ws + OFF_EID);
    int*    PERM = (int*)(ws + OFF_PERM);

    hipMemsetAsync(AUXP, 0, sizeof(float), stream);

    k_embed<<<dim3((TOK * DIMD / 4) / 256), 256, 0, stream>>>(input_ids, tok_emb, pos_emb, X, XB);

    const int nq = 3 * DIMD * DIMD / 8;
    const int no = DIMD * DIMD / 8;
    int di = 0, mi = 0;
    for (int l = 0; l < 6; ++l) {
        const int moe = (l == 1 || l == 3 || l == 5);
        // --- per-layer weight conversion fp32->bf16 (single segmented launch) ---
        {
            const float* s2; const float* s3; int n2, n3;
            if (moe) {
                s2 = mW1 + (size_t)mi * NEXP * FF2 * DIMD;  n2 = NEXP * FF2 * DIMD / 8;
                s3 = mW2 + (size_t)mi * NEXP * DIMD * FFD;  n3 = NEXP * DIMD * FFD / 8;
            } else {
                s2 = dW1 + (size_t)di * FF2 * DIMD;         n2 = FF2 * DIMD / 8;
                s3 = dW2 + (size_t)di * (size_t)DIMD * FFD; n3 = DIMD * FFD / 8;
            }
            int ntot = nq + no + n2 + n3;
            k_cvt4<<<dim3((ntot + 255) / 256), 256, 0, stream>>>(
                wqkv + (size_t)l * 3 * DIMD * DIMD, WQB, nq,
                wo   + (size_t)l * DIMD * DIMD,     WOB, no,
                s2, W1B, n2,
                s3, W2B, n3);
        }
        // QKV projection (bf16 -> bf16)
        k_mm<0,0><<<dim3(3 * DIMD / 128, TOK / 128), 256, 0, stream>>>(
            XB, WQB, bqkv + (size_t)l * 3 * DIMD, QKV, 3 * DIMD, DIMD, DIMD,
            nullptr, nullptr, nullptr, nullptr, nullptr);
        // attention
        k_attn<<<dim3(NB_ * NH, SEQ / 64), 256, 0, stream>>>(QKV, G);
        // output projection (bf16 -> bf16 FB)
        k_mm<0,0><<<dim3(DIMD / 128, TOK / 128), 256, 0, stream>>>(
            G, WOB, bo + (size_t)l * DIMD, FB, DIMD, DIMD, DIMD,
            nullptr, nullptr, nullptr, nullptr, nullptr);
        k_ln<<<TOK / 4, 256, 0, stream>>>(X, FB, ln1g + (size_t)l * DIMD, ln1b + (size_t)l * DIMD, XB);

        if (moe) {
            hipMemsetAsync(SUMS, 0, 64, stream);
            k_gate<<<64, 256, 0, stream>>>(X,
                gAw + (size_t)mi * 2 * DIMD, gAb + (size_t)mi * 2,
                gBw + (size_t)mi * 2 * DIMD, gBb + (size_t)mi * 2,
                SUMS, CNTS, EID);
            k_offsets<<<1, 1, 0, stream>>>(CNTS + 4, OFFS, CURS, NBLK, BLKE, BLKB);
            k_scatter<<<TOK / 256, 256, 0, stream>>>(EID, OFFS, CURS, PERM);
            k_w1g<1><<<dim3(FFD / 128, 68), 256, 0, stream>>>(
                XB, W1B, mB1 + (size_t)mi * NEXP * FF2, Gg,
                PERM, OFFS, BLKE, BLKB, NBLK);
            k_mm<0,1><<<dim3(DIMD / 128, 68), 256, 0, stream>>>(
                Gg, W2B, mB2 + (size_t)mi * NEXP * DIMD, FB, DIMD, FFD, FFD,
                PERM, OFFS, BLKE, BLKB, NBLK);
            k_aux<<<1, 1, 0, stream>>>(SUMS, CNTS, AUXP);
            ++mi;
        } else {
            k_w1g<0><<<dim3(FFD / 128, TOK / 128), 256, 0, stream>>>(
                XB, W1B, dB1 + (size_t)di * FF2, Gg,
                nullptr, nullptr, nullptr, nullptr, nullptr);
            k_mm<0,0><<<dim3(DIMD / 128, TOK / 128), 256, 0, stream>>>(
                Gg, W2B, dB2 + (size_t)di * DIMD, FB, DIMD, FFD, FFD,
                nullptr, nullptr, nullptr, nullptr, nullptr);
            ++di;
        }
        k_ln<<<TOK / 4, 256, 0, stream>>>(X, FB, ln2g + (size_t)l * DIMD, ln2b + (size_t)l * DIMD, XB);
    }

    k_rep<<<dim3((NB_ * DIMD + 255) / 256), 256, 0, stream>>>(X, REP);
    k_cls1<<<dim3(NB_ * DIMD / 4), 256, 0, stream>>>(REP, cW1, cB1, HCLS);
    k_cls2<<<dim3((NB_ * CCLS + 3) / 4), 256, 0, stream>>>(HCLS, cW2, cB2, out);
    k_writeaux<<<1, 1, 0, stream>>>(AUXP, out);
}

// Round 16
// 2925.547 us; speedup vs baseline: 1.0465x; 1.0064x over previous
//
#include <hip/hip_runtime.h>
#include <cstddef>

#define TOK   8192
#define DIMD  768
#define NH    12
#define DHD   64
#define SEQ   512
#define NB_   16
#define FFD   3072
#define NEXP  4
#define CCLS  10
#define FF2   (2*FFD)

typedef short bf16x8 __attribute__((ext_vector_type(8)));
typedef float f32x4  __attribute__((ext_vector_type(4)));

// ---------------- workspace layout (float-slot units) ----------------
static const size_t OFF_X    = 0;                                   // TOK*D fp32
static const size_t OFF_XB   = OFF_X   + (size_t)TOK*DIMD;          // TOK*D bf16
static const size_t OFF_F    = OFF_XB  + (size_t)TOK*DIMD/2;        // TOK*D bf16 (residual branch)
static const size_t OFF_SH   = OFF_F   + (size_t)TOK*DIMD;          // shared: QKV+attnG | Gglu
static const size_t SH_FL    = (size_t)8704*FF2/2;
static const size_t OFF_WQ   = OFF_SH  + SH_FL;                     // qkv weights bf16
static const size_t OFF_WOB  = OFF_WQ  + (size_t)3*DIMD*DIMD/2;
static const size_t OFF_W1B  = OFF_WOB + (size_t)DIMD*DIMD/2;       // up to 4 experts
static const size_t OFF_W2B  = OFF_W1B + (size_t)NEXP*FF2*DIMD/2;
static const size_t OFF_REP  = OFF_W2B + (size_t)NEXP*DIMD*FFD/2;
static const size_t OFF_HCLS = OFF_REP + (size_t)NB_*DIMD;
static const size_t OFF_STAT = OFF_HCLS+ (size_t)NB_*DIMD;          // 3 x 8 floats (per-MoE-layer sums)
static const size_t OFF_INT  = OFF_STAT+ 24;                        // 200 int slots
static const size_t OFF_AUX  = OFF_INT + 200;
static const size_t OFF_EID  = OFF_AUX + 1;                         // TOK ints
static const size_t OFF_PERM = OFF_EID + TOK;                       // TOK ints
// INT map: CNTS3[0..47] (3x16), OFFS[48..52], CURS[53..56], NBLK[57], BLKE[58..125], BLKB[126..193]

__device__ __forceinline__ ushort f2bf(float f) {
    union { float f; unsigned u; } v; v.f = f;
    unsigned r = v.u + 0x7FFF + ((v.u >> 16) & 1);   // RNE
    return (ushort)(r >> 16);
}
__device__ __forceinline__ float bf2f(ushort u) {
    union { unsigned u; float f; } v; v.u = ((unsigned)u) << 16;
    return v.f;
}
__device__ __forceinline__ void gload16(const void* g, void* l) {
    __builtin_amdgcn_global_load_lds((const __attribute__((address_space(1))) void*)g,
                                     (__attribute__((address_space(3))) void*)l, 16, 0, 0);
}

// chunked-bijective XCD swizzle (column-major walk) — R10-proven
__device__ __forceinline__ void xcd_swizzle_cm(int& bx, int& by)
{
    int gx = gridDim.x, gy = gridDim.y;
    int bid = blockIdx.x * gy + blockIdx.y;
    int nwg = gx * gy;
    int q = nwg >> 3, r8 = nwg & 7;
    int xcd = bid & 7, loc = bid >> 3;
    int lbid = (xcd < r8 ? xcd * (q + 1) : r8 * (q + 1) + (xcd - r8) * q) + loc;
    bx = lbid / gy;
    by = lbid % gy;
}

// ---------------- segmented weight fp32 -> bf16 conversion (one launch per layer) ----------------
__global__ __launch_bounds__(256) void k_cvt4(const float* __restrict__ s0, ushort* __restrict__ d0, int n0,
                                              const float* __restrict__ s1, ushort* __restrict__ d1, int n1,
                                              const float* __restrict__ s2, ushort* __restrict__ d2, int n2,
                                              const float* __restrict__ s3, ushort* __restrict__ d3, int n3)
{
    int i = blockIdx.x * 256 + threadIdx.x;
    const float* s; ushort* d; int j = i;
    if (j < n0) { s = s0; d = d0; }
    else {
        j -= n0;
        if (j < n1) { s = s1; d = d1; }
        else {
            j -= n1;
            if (j < n2) { s = s2; d = d2; }
            else {
                j -= n2;
                if (j >= n3) return;
                s = s3; d = d3;
            }
        }
    }
    float4 x0 = ((const float4*)s)[j * 2];
    float4 x1 = ((const float4*)s)[j * 2 + 1];
    ushort r[8] = { f2bf(x0.x), f2bf(x0.y), f2bf(x0.z), f2bf(x0.w),
                    f2bf(x1.x), f2bf(x1.y), f2bf(x1.z), f2bf(x1.w) };
    ((uint4*)d)[j] = *(uint4*)r;
}

// ---------------- embedding: X fp32 + Xb bf16 + gate-statistics init ----------------
__global__ __launch_bounds__(256) void k_embed(const int* __restrict__ ids,
                                               const float* __restrict__ te,
                                               const float* __restrict__ pe,
                                               float* __restrict__ x,
                                               ushort* __restrict__ xb,
                                               float* __restrict__ sums3,
                                               int* __restrict__ cnts3,
                                               float* __restrict__ aux)
{
    if (blockIdx.x == 0) {
        int t = threadIdx.x;
        if (t < 24)             sums3[t] = 0.f;
        if (t >= 32 && t < 80)  cnts3[t - 32] = 0;
        if (t == 80)            *aux = 0.f;
    }
    int i = blockIdx.x * 256 + threadIdx.x;
    const int nd4 = DIMD / 4;
    if (i >= TOK * nd4) return;
    int t = i / nd4, d4 = i % nd4;
    int s = t % SEQ;
    int id = ids[t];
    float4 a = ((const float4*)(te + (size_t)id * DIMD))[d4];
    float4 b = ((const float4*)(pe + (size_t)s  * DIMD))[d4];
    float4 o; o.x = a.x + b.x; o.y = a.y + b.y; o.z = a.z + b.z; o.w = a.w + b.w;
    ((float4*)(x + (size_t)t * DIMD))[d4] = o;
    ushort4 ob = make_ushort4(f2bf(o.x), f2bf(o.y), f2bf(o.z), f2bf(o.w));
    *(ushort4*)(xb + (size_t)t * DIMD + d4 * 4) = ob;
}

// ---------------- 128x128 MFMA GEMM (R8/R10-proven 2-barrier loop) ----------------
// slot-major LDS, global_load_lds(16B), double-buffered, one barrier/K-step.
// GATHER: A rows via toks. SCAT: C bf16 scattered to F[token].
template<int GATHER, int SCAT>
__global__ __launch_bounds__(256) void k_mm(const ushort* __restrict__ A,
                                            const ushort* __restrict__ Wb,
                                            const float* __restrict__ bias,
                                            ushort* __restrict__ C_,
                                            int N, int K, int lda,
                                            const int* __restrict__ perm,
                                            const int* __restrict__ offs,
                                            const int* __restrict__ blke,
                                            const int* __restrict__ blkb,
                                            const int* __restrict__ nblk)
{
    constexpr int MOE = GATHER || SCAT;
    __shared__ ushort As[2][4096];
    __shared__ ushort Bs[2][4096];
    __shared__ int    toks[128];
    const int tid = threadIdx.x, lane = tid & 63, w = tid >> 6;
    int bx, by;
    xcd_swizzle_cm(bx, by);
    const int n0 = bx * 128, row0 = by * 128;
    const ushort* W = Wb;
    const float*  bi = bias;
    int lb = 0, cnt = 1 << 30;
    if constexpr (MOE) {
        if (by >= *nblk) return;
        int e = blke[by];
        lb = blkb[by];
        int base = offs[e];
        cnt = offs[e + 1] - base;
        W  += (size_t)e * N * K;
        bi += (size_t)e * N;
        if (tid < 128) { int rg = lb + tid; toks[tid] = perm[base + (rg < cnt ? rg : cnt - 1)]; }
        __syncthreads();
    }
    int ar0, ar1;
    if constexpr (GATHER) { ar0 = toks[lane]; ar1 = toks[64 + lane]; }
    else                  { ar0 = row0 + lane; ar1 = row0 + 64 + lane; }
    const ushort* ap0 = A + (size_t)ar0 * lda + w * 8;
    const ushort* ap1 = A + (size_t)ar1 * lda + w * 8;
    const ushort* bp0 = W + (size_t)(n0 + lane) * K + w * 8;
    const ushort* bp1 = W + (size_t)(n0 + 64 + lane) * K + w * 8;

    const int l15 = lane & 15, l4 = lane >> 4;
    const int wm = w >> 1, wn = w & 1;
    f32x4 acc[4][4] = {};

    gload16(ap0, &As[0][w * 1024]);
    gload16(ap1, &As[0][w * 1024 + 512]);
    gload16(bp0, &Bs[0][w * 1024]);
    gload16(bp1, &Bs[0][w * 1024 + 512]);
    __syncthreads();

    const int NT = K / 32;
    int cur = 0;
    for (int t = 0; t < NT; ++t) {
        if (t + 1 < NT) {
            int ko = (t + 1) * 32;
            gload16(ap0 + ko, &As[cur ^ 1][w * 1024]);
            gload16(ap1 + ko, &As[cur ^ 1][w * 1024 + 512]);
            gload16(bp0 + ko, &Bs[cur ^ 1][w * 1024]);
            gload16(bp1 + ko, &Bs[cur ^ 1][w * 1024 + 512]);
        }
        bf16x8 af[4], bf_[4];
#pragma unroll
        for (int i = 0; i < 4; ++i) {
            af[i]  = *(const bf16x8*)&As[cur][l4 * 1024 + (wm * 64 + i * 16 + l15) * 8];
            bf_[i] = *(const bf16x8*)&Bs[cur][l4 * 1024 + (wn * 64 + i * 16 + l15) * 8];
        }
#pragma unroll
        for (int mi = 0; mi < 4; ++mi)
#pragma unroll
            for (int ni = 0; ni < 4; ++ni)
                acc[mi][ni] = __builtin_amdgcn_mfma_f32_16x16x32_bf16(af[mi], bf_[ni], acc[mi][ni], 0, 0, 0);
        __syncthreads();
        cur ^= 1;
    }
#pragma unroll
    for (int ni = 0; ni < 4; ++ni) {
        int col = n0 + wn * 64 + ni * 16 + l15;
        float bb = bi[col];
#pragma unroll
        for (int mi = 0; mi < 4; ++mi) {
            int ri = wm * 64 + mi * 16 + l4 * 4;
#pragma unroll
            for (int r = 0; r < 4; ++r) {
                float o = acc[mi][ni][r] + bb;
                if constexpr (SCAT) {
                    if (lb + ri + r < cnt)
                        C_[(size_t)toks[ri + r] * N + col] = f2bf(o);
                } else {
                    C_[(size_t)(row0 + ri + r) * N + col] = f2bf(o);
                }
            }
        }
    }
}

// ---------------- W1 + GLU fused epilogue (R8 structure) ----------------
template<int MOE>
__global__ __launch_bounds__(256) void k_w1g(const ushort* __restrict__ A,
                                             const ushort* __restrict__ Wb,
                                             const float* __restrict__ bias,
                                             ushort* __restrict__ G,
                                             const int* __restrict__ perm,
                                             const int* __restrict__ offs,
                                             const int* __restrict__ blke,
                                             const int* __restrict__ blkb,
                                             const int* __restrict__ nblk)
{
    __shared__ ushort As[2][4096];
    __shared__ ushort Bs[2][8192];
    __shared__ int    toks[128];
    const int tid = threadIdx.x, lane = tid & 63, w = tid >> 6;
    int bx, by;
    xcd_swizzle_cm(bx, by);
    const int n0 = bx * 128, row0 = by * 128;
    const ushort* W = Wb;
    const float*  bi = bias;
    if constexpr (MOE) {
        if (by >= *nblk) return;
        int e = blke[by];
        W  += (size_t)e * FF2 * DIMD;
        bi += (size_t)e * FF2;
        int base = offs[e], cnt = offs[e + 1] - base, lb = blkb[by];
        if (tid < 128) { int rg = lb + tid; toks[tid] = perm[base + (rg < cnt ? rg : cnt - 1)]; }
        __syncthreads();
    }
    int ar0, ar1;
    if constexpr (MOE) { ar0 = toks[lane]; ar1 = toks[64 + lane]; }
    else               { ar0 = row0 + lane; ar1 = row0 + 64 + lane; }
    const ushort* ap0  = A + (size_t)ar0 * DIMD + w * 8;
    const ushort* ap1  = A + (size_t)ar1 * DIMD + w * 8;
    const ushort* bpa0 = W + (size_t)(n0 + lane) * DIMD + w * 8;
    const ushort* bpa1 = W + (size_t)(n0 + 64 + lane) * DIMD + w * 8;
    const ushort* bpb0 = W + (size_t)(FFD + n0 + lane) * DIMD + w * 8;
    const ushort* bpb1 = W + (size_t)(FFD + n0 + 64 + lane) * DIMD + w * 8;

    const int l15 = lane & 15, l4 = lane >> 4;
    const int wm = w >> 1, wn = w & 1;
    f32x4 accA[4][4] = {}, accB[4][4] = {};

    gload16(ap0,  &As[0][w * 1024]);
    gload16(ap1,  &As[0][w * 1024 + 512]);
    gload16(bpa0, &Bs[0][w * 2048]);
    gload16(bpa1, &Bs[0][w * 2048 + 512]);
    gload16(bpb0, &Bs[0][w * 2048 + 1024]);
    gload16(bpb1, &Bs[0][w * 2048 + 1536]);
    __syncthreads();

    const int NT = DIMD / 32;
    int cur = 0;
    for (int t = 0; t < NT; ++t) {
        if (t + 1 < NT) {
            int ko = (t + 1) * 32;
            gload16(ap0 + ko,  &As[cur ^ 1][w * 1024]);
            gload16(ap1 + ko,  &As[cur ^ 1][w * 1024 + 512]);
            gload16(bpa0 + ko, &Bs[cur ^ 1][w * 2048]);
            gload16(bpa1 + ko, &Bs[cur ^ 1][w * 2048 + 512]);
            gload16(bpb0 + ko, &Bs[cur ^ 1][w * 2048 + 1024]);
            gload16(bpb1 + ko, &Bs[cur ^ 1][w * 2048 + 1536]);
        }
        bf16x8 af[4], ba[4], bb[4];
#pragma unroll
        for (int i = 0; i < 4; ++i) {
            af[i] = *(const bf16x8*)&As[cur][l4 * 1024 + (wm * 64 + i * 16 + l15) * 8];
            ba[i] = *(const bf16x8*)&Bs[cur][l4 * 2048 + (wn * 64 + i * 16 + l15) * 8];
            bb[i] = *(const bf16x8*)&Bs[cur][l4 * 2048 + 1024 + (wn * 64 + i * 16 + l15) * 8];
        }
#pragma unroll
        for (int mi = 0; mi < 4; ++mi)
#pragma unroll
            for (int ni = 0; ni < 4; ++ni) {
                accA[mi][ni] = __builtin_amdgcn_mfma_f32_16x16x32_bf16(af[mi], ba[ni], accA[mi][ni], 0, 0, 0);
                accB[mi][ni] = __builtin_amdgcn_mfma_f32_16x16x32_bf16(af[mi], bb[ni], accB[mi][ni], 0, 0, 0);
            }
        __syncthreads();
        cur ^= 1;
    }
#pragma unroll
    for (int ni = 0; ni < 4; ++ni) {
        int col = n0 + wn * 64 + ni * 16 + l15;
        float fa = bi[col];
        float fb = bi[FFD + col];
#pragma unroll
        for (int mi = 0; mi < 4; ++mi) {
            int ri = wm * 64 + mi * 16 + l4 * 4;
#pragma unroll
            for (int r = 0; r < 4; ++r) {
                float a = accA[mi][ni][r] + fa;
                float b = accB[mi][ni][r] + fb;
                float g = a * (b / (1.f + __expf(-b)));
                G[(size_t)(row0 + ri + r) * FFD + col] = f2bf(g);
            }
        }
    }
}

// ---------------- MFMA flash attention (packed QKV, R8-proven) ----------------
__global__ __launch_bounds__(256) void k_attn(const ushort* __restrict__ qkv, ushort* __restrict__ out)
{
    __shared__ ushort Qs[64][72];
    __shared__ ushort Ks[64][72];
    __shared__ ushort Vt[64][72];
    __shared__ ushort Ps[4][16][72];
    const int bh = blockIdx.x;
    const int b = bh / NH, h = bh % NH;
    const int qt = blockIdx.y;
    const int tid = threadIdx.x, lane = tid & 63, w = tid >> 6;
    const int l15 = lane & 15, l4 = lane >> 4;
    const int t0 = b * SEQ + qt * 64;
    {
        int r = tid >> 3, c8 = (tid & 7) * 8;
#pragma unroll
        for (int p = 0; p < 2; ++p) {
            int rr = r + p * 32;
            *(uint4*)&Qs[rr][c8] = *(const uint4*)(qkv + (size_t)(t0 + rr) * 3 * DIMD + h * DHD + c8);
        }
    }
    __syncthreads();
    bf16x8 aq[2];
    aq[0] = *(const bf16x8*)&Qs[w*16 + l15][l4*8];
    aq[1] = *(const bf16x8*)&Qs[w*16 + l15][32 + l4*8];
    f32x4 o[4] = {};
    float m[4], lsum[4];
#pragma unroll
    for (int r = 0; r < 4; ++r) { m[r] = -3.0e38f; lsum[r] = 0.f; }
    for (int kt = 0; kt < SEQ; kt += 64) {
        __syncthreads();
        {
            int r = tid >> 3, c8 = (tid & 7) * 8;
#pragma unroll
            for (int p = 0; p < 2; ++p) {
                int rr = r + p * 32;
                const ushort* kp = qkv + (size_t)(b * SEQ + kt + rr) * 3 * DIMD + DIMD + h * DHD;
                *(uint4*)&Ks[rr][c8] = *(const uint4*)(kp + c8);
                uint4 vv = *(const uint4*)(kp + DIMD + c8);
                const ushort* vs = (const ushort*)&vv;
#pragma unroll
                for (int j = 0; j < 8; ++j) Vt[c8 + j][rr] = vs[j];
            }
        }
        __syncthreads();
        f32x4 s[4] = {};
#pragma unroll
        for (int kk = 0; kk < 2; ++kk)
#pragma unroll
            for (int ni = 0; ni < 4; ++ni) {
                bf16x8 bk = *(const bf16x8*)&Ks[ni*16 + l15][kk*32 + l4*8];
                s[ni] = __builtin_amdgcn_mfma_f32_16x16x32_bf16(aq[kk], bk, s[ni], 0, 0, 0);
            }
        float csc[4];
#pragma unroll
        for (int r = 0; r < 4; ++r) {
            float mx = -3.0e38f;
#pragma unroll
            for (int ni = 0; ni < 4; ++ni) { s[ni][r] *= 0.125f; mx = fmaxf(mx, s[ni][r]); }
            mx = fmaxf(mx, __shfl_xor(mx, 1));
            mx = fmaxf(mx, __shfl_xor(mx, 2));
            mx = fmaxf(mx, __shfl_xor(mx, 4));
            mx = fmaxf(mx, __shfl_xor(mx, 8));
            float nm = fmaxf(m[r], mx);
            float c = __expf(m[r] - nm);
            m[r] = nm;
            float ps = 0.f;
#pragma unroll
            for (int ni = 0; ni < 4; ++ni) { s[ni][r] = __expf(s[ni][r] - nm); ps += s[ni][r]; }
            ps += __shfl_xor(ps, 1);
            ps += __shfl_xor(ps, 2);
            ps += __shfl_xor(ps, 4);
            ps += __shfl_xor(ps, 8);
            lsum[r] = lsum[r] * c + ps;
            csc[r] = c;
#pragma unroll
            for (int ni = 0; ni < 4; ++ni)
                Ps[w][l4*4 + r][ni*16 + l15] = f2bf(s[ni][r]);
        }
#pragma unroll
        for (int di = 0; di < 4; ++di)
#pragma unroll
            for (int r = 0; r < 4; ++r) o[di][r] *= csc[r];
        bf16x8 ap[2];
        ap[0] = *(const bf16x8*)&Ps[w][l15][l4*8];
        ap[1] = *(const bf16x8*)&Ps[w][l15][32 + l4*8];
#pragma unroll
        for (int kk = 0; kk < 2; ++kk)
#pragma unroll
            for (int di = 0; di < 4; ++di) {
                bf16x8 bv = *(const bf16x8*)&Vt[di*16 + l15][kk*32 + l4*8];
                o[di] = __builtin_amdgcn_mfma_f32_16x16x32_bf16(ap[kk], bv, o[di], 0, 0, 0);
            }
    }
    float inv[4];
#pragma unroll
    for (int r = 0; r < 4; ++r) inv[r] = 1.f / lsum[r];
#pragma unroll
    for (int di = 0; di < 4; ++di)
#pragma unroll
        for (int r = 0; r < 4; ++r)
            out[(size_t)(t0 + w*16 + l4*4 + r) * DIMD + h * DHD + di*16 + l15] = f2bf(o[di][r] * inv[r]);
}

// ---------------- wave-per-row residual + LayerNorm -> X fp32 + Xb bf16 ----------------
__global__ __launch_bounds__(256) void k_ln(float* __restrict__ x, const ushort* __restrict__ fb,
                                            const float* __restrict__ g, const float* __restrict__ b,
                                            ushort* __restrict__ xb)
{
    const int t = blockIdx.x * 4 + (threadIdx.x >> 6);
    const int lane = threadIdx.x & 63;
    float* xr = x + (size_t)t * DIMD;
    const ushort* fr = fb + (size_t)t * DIMD;
    float v[12];
    float s = 0.f, s2 = 0.f;
#pragma unroll
    for (int j = 0; j < 12; ++j) {
        int d = lane + j * 64;
        float val = xr[d] + bf2f(fr[d]);
        v[j] = val; s += val; s2 = fmaf(val, val, s2);
    }
#pragma unroll
    for (int off = 1; off < 64; off <<= 1) {
        s  += __shfl_xor(s,  off);
        s2 += __shfl_xor(s2, off);
    }
    const float mean = s * (1.f / DIMD);
    const float var  = s2 * (1.f / DIMD) - mean * mean;
    const float rstd = rsqrtf(var + 1e-5f);
#pragma unroll
    for (int j = 0; j < 12; ++j) {
        int d = lane + j * 64;
        float o = (v[j] - mean) * rstd * g[d] + b[d];
        xr[d] = o;
        xb[(size_t)t * DIMD + d] = f2bf(o);
    }
}

// ---------------- MoE gating ----------------
__global__ __launch_bounds__(256) void k_gate(const float* __restrict__ x,
                                              const float* __restrict__ gAw, const float* __restrict__ gAb,
                                              const float* __restrict__ gBw, const float* __restrict__ gBb,
                                              float* __restrict__ sums, int* __restrict__ cnts,
                                              int* __restrict__ e_id)
{
    const int tid = threadIdx.x, lane = tid & 63, wid = tid >> 6;
    const int gw = blockIdx.x * 4 + wid;
    float wA0[12], wA1[12], wB0[12], wB1[12];
#pragma unroll
    for (int i = 0; i < 12; ++i) {
        int d = lane + i * 64;
        wA0[i] = gAw[d]; wA1[i] = gAw[DIMD + d];
        wB0[i] = gBw[d]; wB1[i] = gBw[DIMD + d];
    }
    const float bA0 = gAb[0], bA1 = gAb[1], bB0 = gBb[0], bB1 = gBb[1];
    float sA0 = 0.f, sA1 = 0.f, sB0 = 0.f, sB1 = 0.f;
    int cA1 = 0, cB1 = 0, cE0 = 0, cE1 = 0, cE2 = 0;
    for (int i = 0; i < 32; ++i) {
        int t = gw * 32 + i;
        const float* xr = x + (size_t)t * DIMD;
        float a0 = 0.f, a1 = 0.f, b0 = 0.f, b1 = 0.f;
#pragma unroll
        for (int j = 0; j < 12; ++j) {
            float v = xr[lane + j * 64];
            a0 = fmaf(v, wA0[j], a0); a1 = fmaf(v, wA1[j], a1);
            b0 = fmaf(v, wB0[j], b0); b1 = fmaf(v, wB1[j], b1);
        }
#pragma unroll
        for (int off = 1; off < 64; off <<= 1) {
            a0 += __shfl_xor(a0, off); a1 += __shfl_xor(a1, off);
            b0 += __shfl_xor(b0, off); b1 += __shfl_xor(b1, off);
        }
        a0 += bA0; a1 += bA1; b0 += bB0; b1 += bB1;
        int iA = (a1 > a0) ? 1 : 0;
        int iB = (b1 > b0) ? 1 : 0;
        float mA = fmaxf(a0, a1); float eA0 = __expf(a0 - mA), eA1 = __expf(a1 - mA);
        float dA = 1.f / (eA0 + eA1);
        float mB = fmaxf(b0, b1); float eB0 = __expf(b0 - mB), eB1 = __expf(b1 - mB);
        float dB = 1.f / (eB0 + eB1);
        sA0 += eA0 * dA; sA1 += eA1 * dA;
        sB0 += eB0 * dB; sB1 += eB1 * dB;
        cA1 += iA; cB1 += iB;
        int e = iA * 2 + iB;
        cE0 += (e == 0); cE1 += (e == 1); cE2 += (e == 2);
        if (lane == 0) e_id[t] = e;
    }
    __shared__ float fpart[4][4];
    __shared__ int   ipart[4][8];
    if (lane == 0) {
        fpart[wid][0] = sA0; fpart[wid][1] = sA1; fpart[wid][2] = sB0; fpart[wid][3] = sB1;
        ipart[wid][0] = 32 - cA1; ipart[wid][1] = cA1;
        ipart[wid][2] = 32 - cB1; ipart[wid][3] = cB1;
        ipart[wid][4] = cE0; ipart[wid][5] = cE1; ipart[wid][6] = cE2;
        ipart[wid][7] = 32 - cE0 - cE1 - cE2;
    }
    __syncthreads();
    if (tid < 4)  atomicAdd(sums + tid, fpart[0][tid] + fpart[1][tid] + fpart[2][tid] + fpart[3][tid]);
    else if (tid >= 64 && tid < 72) {
        int k = tid - 64;
        atomicAdd(cnts + k, ipart[0][k] + ipart[1][k] + ipart[2][k] + ipart[3][k]);
    }
}

// offsets + block map + fused aux-loss accumulation
__global__ void k_offsets(const int* __restrict__ cntE, int* __restrict__ offs, int* __restrict__ cursor,
                          int* __restrict__ nblk, int* __restrict__ blke, int* __restrict__ blkb,
                          const float* __restrict__ sums, const int* __restrict__ cnts,
                          float* __restrict__ aux_acc)
{
    if (threadIdx.x == 0) {
        int a = 0, nb = 0;
        for (int e = 0; e < NEXP; ++e) {
            offs[e] = a; a += cntE[e]; cursor[e] = 0;
            int blocks = (cntE[e] + 127) >> 7;
            for (int b = 0; b < blocks; ++b) { blke[nb] = e; blkb[nb] = b * 128; ++nb; }
        }
        offs[NEXP] = a;
        *nblk = nb;
        const float invT2 = 1.f / ((float)TOK * (float)TOK);
        float aA = 2.f * (sums[0] * (float)cnts[0] + sums[1] * (float)cnts[1]) * invT2;
        float aB = 2.f * (sums[2] * (float)cnts[2] + sums[3] * (float)cnts[3]) * invT2;
        *aux_acc += aA + aB;
    }
}

__global__ __launch_bounds__(256) void k_scatter(const int* __restrict__ e_id, const int* __restrict__ offs,
                                                 int* __restrict__ cursor, int* __restrict__ perm)
{
    int t = blockIdx.x * 256 + threadIdx.x;
    int lane = threadIdx.x & 63;
    int e = e_id[t];
#pragma unroll
    for (int eo = 0; eo < NEXP; ++eo) {
        unsigned long long m = __ballot(e == eo);
        if (m == 0ULL) continue;
        int leader = __ffsll((long long)m) - 1;
        int base = 0;
        if (lane == leader) base = atomicAdd(cursor + eo, (int)__popcll(m));
        base = __shfl(base, leader);
        if (e == eo) {
            int lower = (int)__popcll(m & ((1ULL << lane) - 1ULL));
            perm[offs[eo] + base + lower] = t;
        }
    }
}

// ---------------- classifier head ----------------
__global__ __launch_bounds__(256) void k_rep(const float* __restrict__ x, float* __restrict__ rep)
{
    int i = blockIdx.x * 256 + threadIdx.x;
    if (i >= NB_ * DIMD) return;
    int b = i / DIMD, d = i % DIMD;
    float s = 0.f;
    for (int q = 0; q < SEQ; ++q) s += x[((size_t)b * SEQ + q) * DIMD + d];
    rep[i] = s * (1.f / SEQ);
}

__global__ __launch_bounds__(256) void k_cls1(const float* __restrict__ rep, const float* __restrict__ cW1,
                                              const float* __restrict__ cB1, float* __restrict__ hcls)
{
    int w = blockIdx.x * 4 + (threadIdx.x >> 6);
    int lane = threadIdx.x & 63;
    if (w >= NB_ * DIMD) return;
    int b = w / DIMD, i = w % DIMD;
    float s = 0.f;
    for (int d = lane; d < DIMD; d += 64) s += rep[b * DIMD + d] * cW1[(size_t)i * DIMD + d];
    for (int off = 32; off > 0; off >>= 1) s += __shfl_down(s, off);
    if (lane == 0) hcls[w] = fmaxf(s + cB1[i], 0.f);
}

// logits + aux write (fused writeaux)
__global__ __launch_bounds__(256) void k_cls2(const float* __restrict__ hcls, const float* __restrict__ cW2,
                                              const float* __restrict__ cB2, const float* __restrict__ aux_acc,
                                              float* __restrict__ out)
{
    if (blockIdx.x == 0 && threadIdx.x == 0) out[NB_ * CCLS] = *aux_acc;
    int w = blockIdx.x * 4 + (threadIdx.x >> 6);
    int lane = threadIdx.x & 63;
    if (w >= NB_ * CCLS) return;
    int b = w / CCLS, c = w % CCLS;
    float s = 0.f;
    for (int d = lane; d < DIMD; d += 64) s += hcls[b * DIMD + d] * cW2[(size_t)c * DIMD + d];
    for (int off = 32; off > 0; off >>= 1) s += __shfl_down(s, off);
    if (lane == 0) out[w] = s + cB2[c];
}

// ---------------- host launch ----------------
extern "C" void kernel_launch(void* const* d_in, const int* in_sizes, int n_in,
                              void* d_out, int out_size, void* d_ws, size_t ws_size,
                              hipStream_t stream)
{
    const int*   input_ids = (const int*)  d_in[0];
    const float* tok_emb   = (const float*)d_in[1];
    const float* pos_emb   = (const float*)d_in[2];
    const float* wqkv      = (const float*)d_in[3];
    const float* bqkv      = (const float*)d_in[4];
    const float* wo        = (const float*)d_in[5];
    const float* bo        = (const float*)d_in[6];
    const float* ln1g      = (const float*)d_in[7];
    const float* ln1b      = (const float*)d_in[8];
    const float* ln2g      = (const float*)d_in[9];
    const float* ln2b      = (const float*)d_in[10];
    const float* dW1       = (const float*)d_in[11];
    const float* dB1       = (const float*)d_in[12];
    const float* dW2       = (const float*)d_in[13];
    const float* dB2       = (const float*)d_in[14];
    const float* mW1       = (const float*)d_in[15];
    const float* mB1       = (const float*)d_in[16];
    const float* mW2       = (const float*)d_in[17];
    const float* mB2       = (const float*)d_in[18];
    const float* gAw       = (const float*)d_in[19];
    const float* gAb       = (const float*)d_in[20];
    const float* gBw       = (const float*)d_in[21];
    const float* gBb       = (const float*)d_in[22];
    const float* cW1       = (const float*)d_in[23];
    const float* cB1       = (const float*)d_in[24];
    const float* cW2       = (const float*)d_in[25];
    const float* cB2       = (const float*)d_in[26];

    float* out = (float*)d_out;
    float* ws  = (float*)d_ws;

    float*  X    = ws + OFF_X;
    ushort* XB   = (ushort*)(ws + OFF_XB);
    ushort* FB   = (ushort*)(ws + OFF_F);
    ushort* QKV  = (ushort*)(ws + OFF_SH);
    ushort* G    = (ushort*)(ws + OFF_SH + (size_t)TOK * 3 * DIMD / 2);
    ushort* Gg   = (ushort*)(ws + OFF_SH);     // FFN GLU'd activations (8704 x 3072 bf16)
    ushort* WQB  = (ushort*)(ws + OFF_WQ);
    ushort* WOB  = (ushort*)(ws + OFF_WOB);
    ushort* W1B  = (ushort*)(ws + OFF_W1B);
    ushort* W2B  = (ushort*)(ws + OFF_W2B);
    float*  REP  = ws + OFF_REP;
    float*  HCLS = ws + OFF_HCLS;
    float*  SUMS3= ws + OFF_STAT;             // 3 x 8 floats
    int*    INTB = (int*)(ws + OFF_INT);
    int*    CNTS3= INTB;                      // 3 x 16 ints
    int*    OFFS = INTB + 48;                 // 5
    int*    CURS = INTB + 53;                 // 4
    int*    NBLK = INTB + 57;                 // 1
    int*    BLKE = INTB + 58;                 // 68
    int*    BLKB = INTB + 126;                // 68
    float*  AUXP = ws + OFF_AUX;
    int*    EID  = (int*)(ws + OFF_EID);
    int*    PERM = (int*)(ws + OFF_PERM);

    k_embed<<<dim3((TOK * DIMD / 4) / 256), 256, 0, stream>>>(
        input_ids, tok_emb, pos_emb, X, XB, SUMS3, CNTS3, AUXP);

    const int nq = 3 * DIMD * DIMD / 8;
    const int no = DIMD * DIMD / 8;
    int di = 0, mi = 0;
    for (int l = 0; l < 6; ++l) {
        const int moe = (l == 1 || l == 3 || l == 5);
        // --- per-layer weight conversion fp32->bf16 (single segmented launch) ---
        {
            const float* s2; const float* s3; int n2, n3;
            if (moe) {
                s2 = mW1 + (size_t)mi * NEXP * FF2 * DIMD;  n2 = NEXP * FF2 * DIMD / 8;
                s3 = mW2 + (size_t)mi * NEXP * DIMD * FFD;  n3 = NEXP * DIMD * FFD / 8;
            } else {
                s2 = dW1 + (size_t)di * FF2 * DIMD;         n2 = FF2 * DIMD / 8;
                s3 = dW2 + (size_t)di * (size_t)DIMD * FFD; n3 = DIMD * FFD / 8;
            }
            int ntot = nq + no + n2 + n3;
            k_cvt4<<<dim3((ntot + 255) / 256), 256, 0, stream>>>(
                wqkv + (size_t)l * 3 * DIMD * DIMD, WQB, nq,
                wo   + (size_t)l * DIMD * DIMD,     WOB, no,
                s2, W1B, n2,
                s3, W2B, n3);
        }
        // QKV projection (bf16 -> bf16)
        k_mm<0,0><<<dim3(3 * DIMD / 128, TOK / 128), 256, 0, stream>>>(
            XB, WQB, bqkv + (size_t)l * 3 * DIMD, QKV, 3 * DIMD, DIMD, DIMD,
            nullptr, nullptr, nullptr, nullptr, nullptr);
        // attention
        k_attn<<<dim3(NB_ * NH, SEQ / 64), 256, 0, stream>>>(QKV, G);
        // output projection (bf16 -> bf16 FB)
        k_mm<0,0><<<dim3(DIMD / 128, TOK / 128), 256, 0, stream>>>(
            G, WOB, bo + (size_t)l * DIMD, FB, DIMD, DIMD, DIMD,
            nullptr, nullptr, nullptr, nullptr, nullptr);
        k_ln<<<TOK / 4, 256, 0, stream>>>(X, FB, ln1g + (size_t)l * DIMD, ln1b + (size_t)l * DIMD, XB);

        if (moe) {
            float* SUMS = SUMS3 + mi * 8;
            int*   CNTS = CNTS3 + mi * 16;
            k_gate<<<64, 256, 0, stream>>>(X,
                gAw + (size_t)mi * 2 * DIMD, gAb + (size_t)mi * 2,
                gBw + (size_t)mi * 2 * DIMD, gBb + (size_t)mi * 2,
                SUMS, CNTS, EID);
            k_offsets<<<1, 1, 0, stream>>>(CNTS + 4, OFFS, CURS, NBLK, BLKE, BLKB,
                                           SUMS, CNTS, AUXP);
            k_scatter<<<TOK / 256, 256, 0, stream>>>(EID, OFFS, CURS, PERM);
            k_w1g<1><<<dim3(FFD / 128, 68), 256, 0, stream>>>(
                XB, W1B, mB1 + (size_t)mi * NEXP * FF2, Gg,
                PERM, OFFS, BLKE, BLKB, NBLK);
            k_mm<0,1><<<dim3(DIMD / 128, 68), 256, 0, stream>>>(
                Gg, W2B, mB2 + (size_t)mi * NEXP * DIMD, FB, DIMD, FFD, FFD,
                PERM, OFFS, BLKE, BLKB, NBLK);
            ++mi;
        } else {
            k_w1g<0><<<dim3(FFD / 128, TOK / 128), 256, 0, stream>>>(
                XB, W1B, dB1 + (size_t)di * FF2, Gg,
                nullptr, nullptr, nullptr, nullptr, nullptr);
            k_mm<0,0><<<dim3(DIMD / 128, TOK / 128), 256, 0, stream>>>(
                Gg, W2B, dB2 + (size_t)di * DIMD, FB, DIMD, FFD, FFD,
                nullptr, nullptr, nullptr, nullptr, nullptr);
            ++di;
        }
        k_ln<<<TOK / 4, 256, 0, stream>>>(X, FB, ln2g + (size_t)l * DIMD, ln2b + (size_t)l * DIMD, XB);
    }

    k_rep<<<dim3((NB_ * DIMD + 255) / 256), 256, 0, stream>>>(X, REP);
    k_cls1<<<dim3(NB_ * DIMD / 4), 256, 0, stream>>>(REP, cW1, cB1, HCLS);
    k_cls2<<<dim3((NB_ * CCLS + 3) / 4), 256, 0, stream>>>(HCLS, cW2, cB2, AUXP, out);
}

// Round 17
// 2858.557 us; speedup vs baseline: 1.0710x; 1.0234x over previous
//
#include <hip/hip_runtime.h>
#include <cstddef>

#define TOK   8192
#define DIMD  768
#define NH    12
#define DHD   64
#define SEQ   512
#define NB_   16
#define FFD   3072
#define NEXP  4
#define CCLS  10
#define FF2   (2*FFD)

typedef short bf16x8 __attribute__((ext_vector_type(8)));
typedef float f32x4  __attribute__((ext_vector_type(4)));

// ---------------- workspace layout (float-slot units) ----------------
static const size_t OFF_X    = 0;                                   // TOK*D fp32
static const size_t OFF_XB   = OFF_X   + (size_t)TOK*DIMD;          // TOK*D bf16
static const size_t OFF_F    = OFF_XB  + (size_t)TOK*DIMD/2;        // TOK*D bf16 (residual branch)
static const size_t OFF_SH   = OFF_F   + (size_t)TOK*DIMD;          // shared: QKV+attnG | Gglu
static const size_t SH_FL    = (size_t)8704*FF2/2;
static const size_t OFF_WQ   = OFF_SH  + SH_FL;                     // qkv weights bf16
static const size_t OFF_WOB  = OFF_WQ  + (size_t)3*DIMD*DIMD/2;
static const size_t OFF_W1B  = OFF_WOB + (size_t)DIMD*DIMD/2;       // up to 4 experts
static const size_t OFF_W2B  = OFF_W1B + (size_t)NEXP*FF2*DIMD/2;
static const size_t OFF_REP  = OFF_W2B + (size_t)NEXP*DIMD*FFD/2;
static const size_t OFF_HCLS = OFF_REP + (size_t)NB_*DIMD;
static const size_t OFF_STAT = OFF_HCLS+ (size_t)NB_*DIMD;          // 3 x 8 floats (per-MoE-layer sums)
static const size_t OFF_INT  = OFF_STAT+ 24;                        // 200 int slots
static const size_t OFF_AUX  = OFF_INT + 200;
static const size_t OFF_EID  = OFF_AUX + 1;                         // TOK ints
static const size_t OFF_PERM = OFF_EID + TOK;                       // TOK ints
// INT map: CNTS3[0..47] (3x16), OFFS[48..52], CURS[53..56], NBLK[57], BLKE[58..125], BLKB[126..193]

__device__ __forceinline__ ushort f2bf(float f) {
    union { float f; unsigned u; } v; v.f = f;
    unsigned r = v.u + 0x7FFF + ((v.u >> 16) & 1);   // RNE
    return (ushort)(r >> 16);
}
__device__ __forceinline__ float bf2f(ushort u) {
    union { unsigned u; float f; } v; v.u = ((unsigned)u) << 16;
    return v.f;
}
__device__ __forceinline__ void gload16(const void* g, void* l) {
    __builtin_amdgcn_global_load_lds((const __attribute__((address_space(1))) void*)g,
                                     (__attribute__((address_space(3))) void*)l, 16, 0, 0);
}

// chunked-bijective XCD swizzle (column-major walk) — R10-proven
__device__ __forceinline__ void xcd_swizzle_cm(int& bx, int& by)
{
    int gx = gridDim.x, gy = gridDim.y;
    int bid = blockIdx.x * gy + blockIdx.y;
    int nwg = gx * gy;
    int q = nwg >> 3, r8 = nwg & 7;
    int xcd = bid & 7, loc = bid >> 3;
    int lbid = (xcd < r8 ? xcd * (q + 1) : r8 * (q + 1) + (xcd - r8) * q) + loc;
    bx = lbid / gy;
    by = lbid % gy;
}

// ---------------- segmented weight fp32 -> bf16 conversion (one launch per layer) ----------------
__global__ __launch_bounds__(256) void k_cvt4(const float* __restrict__ s0, ushort* __restrict__ d0, int n0,
                                              const float* __restrict__ s1, ushort* __restrict__ d1, int n1,
                                              const float* __restrict__ s2, ushort* __restrict__ d2, int n2,
                                              const float* __restrict__ s3, ushort* __restrict__ d3, int n3)
{
    int i = blockIdx.x * 256 + threadIdx.x;
    const float* s; ushort* d; int j = i;
    if (j < n0) { s = s0; d = d0; }
    else {
        j -= n0;
        if (j < n1) { s = s1; d = d1; }
        else {
            j -= n1;
            if (j < n2) { s = s2; d = d2; }
            else {
                j -= n2;
                if (j >= n3) return;
                s = s3; d = d3;
            }
        }
    }
    float4 x0 = ((const float4*)s)[j * 2];
    float4 x1 = ((const float4*)s)[j * 2 + 1];
    ushort r[8] = { f2bf(x0.x), f2bf(x0.y), f2bf(x0.z), f2bf(x0.w),
                    f2bf(x1.x), f2bf(x1.y), f2bf(x1.z), f2bf(x1.w) };
    ((uint4*)d)[j] = *(uint4*)r;
}

// ---------------- embedding: X fp32 + Xb bf16 + gate-statistics init ----------------
__global__ __launch_bounds__(256) void k_embed(const int* __restrict__ ids,
                                               const float* __restrict__ te,
                                               const float* __restrict__ pe,
                                               float* __restrict__ x,
                                               ushort* __restrict__ xb,
                                               float* __restrict__ sums3,
                                               int* __restrict__ cnts3,
                                               float* __restrict__ aux)
{
    if (blockIdx.x == 0) {
        int t = threadIdx.x;
        if (t < 24)             sums3[t] = 0.f;
        if (t >= 32 && t < 80)  cnts3[t - 32] = 0;
        if (t == 80)            *aux = 0.f;
    }
    int i = blockIdx.x * 256 + threadIdx.x;
    const int nd4 = DIMD / 4;
    if (i >= TOK * nd4) return;
    int t = i / nd4, d4 = i % nd4;
    int s = t % SEQ;
    int id = ids[t];
    float4 a = ((const float4*)(te + (size_t)id * DIMD))[d4];
    float4 b = ((const float4*)(pe + (size_t)s  * DIMD))[d4];
    float4 o; o.x = a.x + b.x; o.y = a.y + b.y; o.z = a.z + b.z; o.w = a.w + b.w;
    ((float4*)(x + (size_t)t * DIMD))[d4] = o;
    ushort4 ob = make_ushort4(f2bf(o.x), f2bf(o.y), f2bf(o.z), f2bf(o.w));
    *(ushort4*)(xb + (size_t)t * DIMD + d4 * 4) = ob;
}

// ---------------- 128x128 MFMA GEMM (R8/R10-proven 2-barrier loop) ----------------
template<int GATHER, int SCAT>
__global__ __launch_bounds__(256) void k_mm(const ushort* __restrict__ A,
                                            const ushort* __restrict__ Wb,
                                            const float* __restrict__ bias,
                                            ushort* __restrict__ C_,
                                            int N, int K, int lda,
                                            const int* __restrict__ perm,
                                            const int* __restrict__ offs,
                                            const int* __restrict__ blke,
                                            const int* __restrict__ blkb,
                                            const int* __restrict__ nblk)
{
    constexpr int MOE = GATHER || SCAT;
    __shared__ ushort As[2][4096];
    __shared__ ushort Bs[2][4096];
    __shared__ int    toks[128];
    const int tid = threadIdx.x, lane = tid & 63, w = tid >> 6;
    int bx, by;
    xcd_swizzle_cm(bx, by);
    const int n0 = bx * 128, row0 = by * 128;
    const ushort* W = Wb;
    const float*  bi = bias;
    int lb = 0, cnt = 1 << 30;
    if constexpr (MOE) {
        if (by >= *nblk) return;
        int e = blke[by];
        lb = blkb[by];
        int base = offs[e];
        cnt = offs[e + 1] - base;
        W  += (size_t)e * N * K;
        bi += (size_t)e * N;
        if (tid < 128) { int rg = lb + tid; toks[tid] = perm[base + (rg < cnt ? rg : cnt - 1)]; }
        __syncthreads();
    }
    int ar0, ar1;
    if constexpr (GATHER) { ar0 = toks[lane]; ar1 = toks[64 + lane]; }
    else                  { ar0 = row0 + lane; ar1 = row0 + 64 + lane; }
    const ushort* ap0 = A + (size_t)ar0 * lda + w * 8;
    const ushort* ap1 = A + (size_t)ar1 * lda + w * 8;
    const ushort* bp0 = W + (size_t)(n0 + lane) * K + w * 8;
    const ushort* bp1 = W + (size_t)(n0 + 64 + lane) * K + w * 8;

    const int l15 = lane & 15, l4 = lane >> 4;
    const int wm = w >> 1, wn = w & 1;
    f32x4 acc[4][4] = {};

    gload16(ap0, &As[0][w * 1024]);
    gload16(ap1, &As[0][w * 1024 + 512]);
    gload16(bp0, &Bs[0][w * 1024]);
    gload16(bp1, &Bs[0][w * 1024 + 512]);
    __syncthreads();

    const int NT = K / 32;
    int cur = 0;
    for (int t = 0; t < NT; ++t) {
        if (t + 1 < NT) {
            int ko = (t + 1) * 32;
            gload16(ap0 + ko, &As[cur ^ 1][w * 1024]);
            gload16(ap1 + ko, &As[cur ^ 1][w * 1024 + 512]);
            gload16(bp0 + ko, &Bs[cur ^ 1][w * 1024]);
            gload16(bp1 + ko, &Bs[cur ^ 1][w * 1024 + 512]);
        }
        bf16x8 af[4], bf_[4];
#pragma unroll
        for (int i = 0; i < 4; ++i) {
            af[i]  = *(const bf16x8*)&As[cur][l4 * 1024 + (wm * 64 + i * 16 + l15) * 8];
            bf_[i] = *(const bf16x8*)&Bs[cur][l4 * 1024 + (wn * 64 + i * 16 + l15) * 8];
        }
#pragma unroll
        for (int mi = 0; mi < 4; ++mi)
#pragma unroll
            for (int ni = 0; ni < 4; ++ni)
                acc[mi][ni] = __builtin_amdgcn_mfma_f32_16x16x32_bf16(af[mi], bf_[ni], acc[mi][ni], 0, 0, 0);
        __syncthreads();
        cur ^= 1;
    }
#pragma unroll
    for (int ni = 0; ni < 4; ++ni) {
        int col = n0 + wn * 64 + ni * 16 + l15;
        float bb = bi[col];
#pragma unroll
        for (int mi = 0; mi < 4; ++mi) {
            int ri = wm * 64 + mi * 16 + l4 * 4;
#pragma unroll
            for (int r = 0; r < 4; ++r) {
                float o = acc[mi][ni][r] + bb;
                if constexpr (SCAT) {
                    if (lb + ri + r < cnt)
                        C_[(size_t)toks[ri + r] * N + col] = f2bf(o);
                } else {
                    C_[(size_t)(row0 + ri + r) * N + col] = f2bf(o);
                }
            }
        }
    }
}

// ---------------- W1 + GLU fused epilogue (R8 structure) ----------------
template<int MOE>
__global__ __launch_bounds__(256) void k_w1g(const ushort* __restrict__ A,
                                             const ushort* __restrict__ Wb,
                                             const float* __restrict__ bias,
                                             ushort* __restrict__ G,
                                             const int* __restrict__ perm,
                                             const int* __restrict__ offs,
                                             const int* __restrict__ blke,
                                             const int* __restrict__ blkb,
                                             const int* __restrict__ nblk)
{
    __shared__ ushort As[2][4096];
    __shared__ ushort Bs[2][8192];
    __shared__ int    toks[128];
    const int tid = threadIdx.x, lane = tid & 63, w = tid >> 6;
    int bx, by;
    xcd_swizzle_cm(bx, by);
    const int n0 = bx * 128, row0 = by * 128;
    const ushort* W = Wb;
    const float*  bi = bias;
    if constexpr (MOE) {
        if (by >= *nblk) return;
        int e = blke[by];
        W  += (size_t)e * FF2 * DIMD;
        bi += (size_t)e * FF2;
        int base = offs[e], cnt = offs[e + 1] - base, lb = blkb[by];
        if (tid < 128) { int rg = lb + tid; toks[tid] = perm[base + (rg < cnt ? rg : cnt - 1)]; }
        __syncthreads();
    }
    int ar0, ar1;
    if constexpr (MOE) { ar0 = toks[lane]; ar1 = toks[64 + lane]; }
    else               { ar0 = row0 + lane; ar1 = row0 + 64 + lane; }
    const ushort* ap0  = A + (size_t)ar0 * DIMD + w * 8;
    const ushort* ap1  = A + (size_t)ar1 * DIMD + w * 8;
    const ushort* bpa0 = W + (size_t)(n0 + lane) * DIMD + w * 8;
    const ushort* bpa1 = W + (size_t)(n0 + 64 + lane) * DIMD + w * 8;
    const ushort* bpb0 = W + (size_t)(FFD + n0 + lane) * DIMD + w * 8;
    const ushort* bpb1 = W + (size_t)(FFD + n0 + 64 + lane) * DIMD + w * 8;

    const int l15 = lane & 15, l4 = lane >> 4;
    const int wm = w >> 1, wn = w & 1;
    f32x4 accA[4][4] = {}, accB[4][4] = {};

    gload16(ap0,  &As[0][w * 1024]);
    gload16(ap1,  &As[0][w * 1024 + 512]);
    gload16(bpa0, &Bs[0][w * 2048]);
    gload16(bpa1, &Bs[0][w * 2048 + 512]);
    gload16(bpb0, &Bs[0][w * 2048 + 1024]);
    gload16(bpb1, &Bs[0][w * 2048 + 1536]);
    __syncthreads();

    const int NT = DIMD / 32;
    int cur = 0;
    for (int t = 0; t < NT; ++t) {
        if (t + 1 < NT) {
            int ko = (t + 1) * 32;
            gload16(ap0 + ko,  &As[cur ^ 1][w * 1024]);
            gload16(ap1 + ko,  &As[cur ^ 1][w * 1024 + 512]);
            gload16(bpa0 + ko, &Bs[cur ^ 1][w * 2048]);
            gload16(bpa1 + ko, &Bs[cur ^ 1][w * 2048 + 512]);
            gload16(bpb0 + ko, &Bs[cur ^ 1][w * 2048 + 1024]);
            gload16(bpb1 + ko, &Bs[cur ^ 1][w * 2048 + 1536]);
        }
        bf16x8 af[4], ba[4], bb[4];
#pragma unroll
        for (int i = 0; i < 4; ++i) {
            af[i] = *(const bf16x8*)&As[cur][l4 * 1024 + (wm * 64 + i * 16 + l15) * 8];
            ba[i] = *(const bf16x8*)&Bs[cur][l4 * 2048 + (wn * 64 + i * 16 + l15) * 8];
            bb[i] = *(const bf16x8*)&Bs[cur][l4 * 2048 + 1024 + (wn * 64 + i * 16 + l15) * 8];
        }
#pragma unroll
        for (int mi = 0; mi < 4; ++mi)
#pragma unroll
            for (int ni = 0; ni < 4; ++ni) {
                accA[mi][ni] = __builtin_amdgcn_mfma_f32_16x16x32_bf16(af[mi], ba[ni], accA[mi][ni], 0, 0, 0);
                accB[mi][ni] = __builtin_amdgcn_mfma_f32_16x16x32_bf16(af[mi], bb[ni], accB[mi][ni], 0, 0, 0);
            }
        __syncthreads();
        cur ^= 1;
    }
#pragma unroll
    for (int ni = 0; ni < 4; ++ni) {
        int col = n0 + wn * 64 + ni * 16 + l15;
        float fa = bi[col];
        float fb = bi[FFD + col];
#pragma unroll
        for (int mi = 0; mi < 4; ++mi) {
            int ri = wm * 64 + mi * 16 + l4 * 4;
#pragma unroll
            for (int r = 0; r < 4; ++r) {
                float a = accA[mi][ni][r] + fa;
                float b = accB[mi][ni][r] + fb;
                float g = a * (b / (1.f + __expf(-b)));
                G[(size_t)(row0 + ri + r) * FFD + col] = f2bf(g);
            }
        }
    }
}

// ---------------- MFMA flash attention: 2 q-tiles per block (K/V staged once) ----------------
__global__ __launch_bounds__(256) void k_attn(const ushort* __restrict__ qkv, ushort* __restrict__ out)
{
    __shared__ ushort Qs[2][64][72];
    __shared__ ushort Ks[64][72];
    __shared__ ushort Vt[64][72];
    __shared__ ushort Ps[4][16][72];
    const int bh = blockIdx.x;
    const int b = bh / NH, h = bh % NH;
    const int qp = blockIdx.y;                       // q-pair index (0..3)
    const int tid = threadIdx.x, lane = tid & 63, w = tid >> 6;
    const int l15 = lane & 15, l4 = lane >> 4;
    const int t0 = b * SEQ + qp * 128;               // first of 128 q rows
    {
        int r = tid >> 3, c8 = (tid & 7) * 8;
#pragma unroll
        for (int sub = 0; sub < 2; ++sub)
#pragma unroll
            for (int p = 0; p < 2; ++p) {
                int rr = r + p * 32;
                *(uint4*)&Qs[sub][rr][c8] =
                    *(const uint4*)(qkv + (size_t)(t0 + sub * 64 + rr) * 3 * DIMD + h * DHD + c8);
            }
    }
    __syncthreads();
    bf16x8 aq[2][2];
#pragma unroll
    for (int sub = 0; sub < 2; ++sub) {
        aq[sub][0] = *(const bf16x8*)&Qs[sub][w*16 + l15][l4*8];
        aq[sub][1] = *(const bf16x8*)&Qs[sub][w*16 + l15][32 + l4*8];
    }
    f32x4 o[2][4] = {};
    float m[2][4], lsum[2][4];
#pragma unroll
    for (int sub = 0; sub < 2; ++sub)
#pragma unroll
        for (int r = 0; r < 4; ++r) { m[sub][r] = -3.0e38f; lsum[sub][r] = 0.f; }
    for (int kt = 0; kt < SEQ; kt += 64) {
        __syncthreads();
        {
            int r = tid >> 3, c8 = (tid & 7) * 8;
#pragma unroll
            for (int p = 0; p < 2; ++p) {
                int rr = r + p * 32;
                const ushort* kp = qkv + (size_t)(b * SEQ + kt + rr) * 3 * DIMD + DIMD + h * DHD;
                *(uint4*)&Ks[rr][c8] = *(const uint4*)(kp + c8);
                uint4 vv = *(const uint4*)(kp + DIMD + c8);
                const ushort* vs = (const ushort*)&vv;
#pragma unroll
                for (int j = 0; j < 8; ++j) Vt[c8 + j][rr] = vs[j];
            }
        }
        __syncthreads();
#pragma unroll
        for (int sub = 0; sub < 2; ++sub) {
            f32x4 s[4] = {};
#pragma unroll
            for (int kk = 0; kk < 2; ++kk)
#pragma unroll
                for (int ni = 0; ni < 4; ++ni) {
                    bf16x8 bk = *(const bf16x8*)&Ks[ni*16 + l15][kk*32 + l4*8];
                    s[ni] = __builtin_amdgcn_mfma_f32_16x16x32_bf16(aq[sub][kk], bk, s[ni], 0, 0, 0);
                }
            float csc[4];
#pragma unroll
            for (int r = 0; r < 4; ++r) {
                float mx = -3.0e38f;
#pragma unroll
                for (int ni = 0; ni < 4; ++ni) { s[ni][r] *= 0.125f; mx = fmaxf(mx, s[ni][r]); }
                mx = fmaxf(mx, __shfl_xor(mx, 1));
                mx = fmaxf(mx, __shfl_xor(mx, 2));
                mx = fmaxf(mx, __shfl_xor(mx, 4));
                mx = fmaxf(mx, __shfl_xor(mx, 8));
                float nm = fmaxf(m[sub][r], mx);
                float c = __expf(m[sub][r] - nm);
                m[sub][r] = nm;
                float ps = 0.f;
#pragma unroll
                for (int ni = 0; ni < 4; ++ni) { s[ni][r] = __expf(s[ni][r] - nm); ps += s[ni][r]; }
                ps += __shfl_xor(ps, 1);
                ps += __shfl_xor(ps, 2);
                ps += __shfl_xor(ps, 4);
                ps += __shfl_xor(ps, 8);
                lsum[sub][r] = lsum[sub][r] * c + ps;
                csc[r] = c;
#pragma unroll
                for (int ni = 0; ni < 4; ++ni)
                    Ps[w][l4*4 + r][ni*16 + l15] = f2bf(s[ni][r]);
            }
#pragma unroll
            for (int di = 0; di < 4; ++di)
#pragma unroll
                for (int r = 0; r < 4; ++r) o[sub][di][r] *= csc[r];
            bf16x8 ap[2];
            ap[0] = *(const bf16x8*)&Ps[w][l15][l4*8];
            ap[1] = *(const bf16x8*)&Ps[w][l15][32 + l4*8];
#pragma unroll
            for (int kk = 0; kk < 2; ++kk)
#pragma unroll
                for (int di = 0; di < 4; ++di) {
                    bf16x8 bv = *(const bf16x8*)&Vt[di*16 + l15][kk*32 + l4*8];
                    o[sub][di] = __builtin_amdgcn_mfma_f32_16x16x32_bf16(ap[kk], bv, o[sub][di], 0, 0, 0);
                }
        }
    }
#pragma unroll
    for (int sub = 0; sub < 2; ++sub) {
        float inv[4];
#pragma unroll
        for (int r = 0; r < 4; ++r) inv[r] = 1.f / lsum[sub][r];
#pragma unroll
        for (int di = 0; di < 4; ++di)
#pragma unroll
            for (int r = 0; r < 4; ++r)
                out[(size_t)(t0 + sub*64 + w*16 + l4*4 + r) * DIMD + h * DHD + di*16 + l15] =
                    f2bf(o[sub][di][r] * inv[r]);
    }
}

// ---------------- wave-per-row residual + LayerNorm -> X fp32 + Xb bf16 ----------------
__global__ __launch_bounds__(256) void k_ln(float* __restrict__ x, const ushort* __restrict__ fb,
                                            const float* __restrict__ g, const float* __restrict__ b,
                                            ushort* __restrict__ xb)
{
    const int t = blockIdx.x * 4 + (threadIdx.x >> 6);
    const int lane = threadIdx.x & 63;
    float* xr = x + (size_t)t * DIMD;
    const ushort* fr = fb + (size_t)t * DIMD;
    float v[12];
    float s = 0.f, s2 = 0.f;
#pragma unroll
    for (int j = 0; j < 12; ++j) {
        int d = lane + j * 64;
        float val = xr[d] + bf2f(fr[d]);
        v[j] = val; s += val; s2 = fmaf(val, val, s2);
    }
#pragma unroll
    for (int off = 1; off < 64; off <<= 1) {
        s  += __shfl_xor(s,  off);
        s2 += __shfl_xor(s2, off);
    }
    const float mean = s * (1.f / DIMD);
    const float var  = s2 * (1.f / DIMD) - mean * mean;
    const float rstd = rsqrtf(var + 1e-5f);
#pragma unroll
    for (int j = 0; j < 12; ++j) {
        int d = lane + j * 64;
        float o = (v[j] - mean) * rstd * g[d] + b[d];
        xr[d] = o;
        xb[(size_t)t * DIMD + d] = f2bf(o);
    }
}

// ---------------- MoE gating ----------------
__global__ __launch_bounds__(256) void k_gate(const float* __restrict__ x,
                                              const float* __restrict__ gAw, const float* __restrict__ gAb,
                                              const float* __restrict__ gBw, const float* __restrict__ gBb,
                                              float* __restrict__ sums, int* __restrict__ cnts,
                                              int* __restrict__ e_id)
{
    const int tid = threadIdx.x, lane = tid & 63, wid = tid >> 6;
    const int gw = blockIdx.x * 4 + wid;
    float wA0[12], wA1[12], wB0[12], wB1[12];
#pragma unroll
    for (int i = 0; i < 12; ++i) {
        int d = lane + i * 64;
        wA0[i] = gAw[d]; wA1[i] = gAw[DIMD + d];
        wB0[i] = gBw[d]; wB1[i] = gBw[DIMD + d];
    }
    const float bA0 = gAb[0], bA1 = gAb[1], bB0 = gBb[0], bB1 = gBb[1];
    float sA0 = 0.f, sA1 = 0.f, sB0 = 0.f, sB1 = 0.f;
    int cA1 = 0, cB1 = 0, cE0 = 0, cE1 = 0, cE2 = 0;
    for (int i = 0; i < 32; ++i) {
        int t = gw * 32 + i;
        const float* xr = x + (size_t)t * DIMD;
        float a0 = 0.f, a1 = 0.f, b0 = 0.f, b1 = 0.f;
#pragma unroll
        for (int j = 0; j < 12; ++j) {
            float v = xr[lane + j * 64];
            a0 = fmaf(v, wA0[j], a0); a1 = fmaf(v, wA1[j], a1);
            b0 = fmaf(v, wB0[j], b0); b1 = fmaf(v, wB1[j], b1);
        }
#pragma unroll
        for (int off = 1; off < 64; off <<= 1) {
            a0 += __shfl_xor(a0, off); a1 += __shfl_xor(a1, off);
            b0 += __shfl_xor(b0, off); b1 += __shfl_xor(b1, off);
        }
        a0 += bA0; a1 += bA1; b0 += bB0; b1 += bB1;
        int iA = (a1 > a0) ? 1 : 0;
        int iB = (b1 > b0) ? 1 : 0;
        float mA = fmaxf(a0, a1); float eA0 = __expf(a0 - mA), eA1 = __expf(a1 - mA);
        float dA = 1.f / (eA0 + eA1);
        float mB = fmaxf(b0, b1); float eB0 = __expf(b0 - mB), eB1 = __expf(b1 - mB);
        float dB = 1.f / (eB0 + eB1);
        sA0 += eA0 * dA; sA1 += eA1 * dA;
        sB0 += eB0 * dB; sB1 += eB1 * dB;
        cA1 += iA; cB1 += iB;
        int e = iA * 2 + iB;
        cE0 += (e == 0); cE1 += (e == 1); cE2 += (e == 2);
        if (lane == 0) e_id[t] = e;
    }
    __shared__ float fpart[4][4];
    __shared__ int   ipart[4][8];
    if (lane == 0) {
        fpart[wid][0] = sA0; fpart[wid][1] = sA1; fpart[wid][2] = sB0; fpart[wid][3] = sB1;
        ipart[wid][0] = 32 - cA1; ipart[wid][1] = cA1;
        ipart[wid][2] = 32 - cB1; ipart[wid][3] = cB1;
        ipart[wid][4] = cE0; ipart[wid][5] = cE1; ipart[wid][6] = cE2;
        ipart[wid][7] = 32 - cE0 - cE1 - cE2;
    }
    __syncthreads();
    if (tid < 4)  atomicAdd(sums + tid, fpart[0][tid] + fpart[1][tid] + fpart[2][tid] + fpart[3][tid]);
    else if (tid >= 64 && tid < 72) {
        int k = tid - 64;
        atomicAdd(cnts + k, ipart[0][k] + ipart[1][k] + ipart[2][k] + ipart[3][k]);
    }
}

// offsets + block map + fused aux-loss accumulation
__global__ void k_offsets(const int* __restrict__ cntE, int* __restrict__ offs, int* __restrict__ cursor,
                          int* __restrict__ nblk, int* __restrict__ blke, int* __restrict__ blkb,
                          const float* __restrict__ sums, const int* __restrict__ cnts,
                          float* __restrict__ aux_acc)
{
    if (threadIdx.x == 0) {
        int a = 0, nb = 0;
        for (int e = 0; e < NEXP; ++e) {
            offs[e] = a; a += cntE[e]; cursor[e] = 0;
            int blocks = (cntE[e] + 127) >> 7;
            for (int b = 0; b < blocks; ++b) { blke[nb] = e; blkb[nb] = b * 128; ++nb; }
        }
        offs[NEXP] = a;
        *nblk = nb;
        const float invT2 = 1.f / ((float)TOK * (float)TOK);
        float aA = 2.f * (sums[0] * (float)cnts[0] + sums[1] * (float)cnts[1]) * invT2;
        float aB = 2.f * (sums[2] * (float)cnts[2] + sums[3] * (float)cnts[3]) * invT2;
        *aux_acc += aA + aB;
    }
}

__global__ __launch_bounds__(256) void k_scatter(const int* __restrict__ e_id, const int* __restrict__ offs,
                                                 int* __restrict__ cursor, int* __restrict__ perm)
{
    int t = blockIdx.x * 256 + threadIdx.x;
    int lane = threadIdx.x & 63;
    int e = e_id[t];
#pragma unroll
    for (int eo = 0; eo < NEXP; ++eo) {
        unsigned long long m = __ballot(e == eo);
        if (m == 0ULL) continue;
        int leader = __ffsll((long long)m) - 1;
        int base = 0;
        if (lane == leader) base = atomicAdd(cursor + eo, (int)__popcll(m));
        base = __shfl(base, leader);
        if (e == eo) {
            int lower = (int)__popcll(m & ((1ULL << lane) - 1ULL));
            perm[offs[eo] + base + lower] = t;
        }
    }
}

// ---------------- classifier head ----------------
__global__ __launch_bounds__(256) void k_rep(const float* __restrict__ x, float* __restrict__ rep)
{
    int i = blockIdx.x * 256 + threadIdx.x;
    if (i >= NB_ * DIMD) return;
    int b = i / DIMD, d = i % DIMD;
    float s = 0.f;
    for (int q = 0; q < SEQ; ++q) s += x[((size_t)b * SEQ + q) * DIMD + d];
    rep[i] = s * (1.f / SEQ);
}

__global__ __launch_bounds__(256) void k_cls1(const float* __restrict__ rep, const float* __restrict__ cW1,
                                              const float* __restrict__ cB1, float* __restrict__ hcls)
{
    int w = blockIdx.x * 4 + (threadIdx.x >> 6);
    int lane = threadIdx.x & 63;
    if (w >= NB_ * DIMD) return;
    int b = w / DIMD, i = w % DIMD;
    float s = 0.f;
    for (int d = lane; d < DIMD; d += 64) s += rep[b * DIMD + d] * cW1[(size_t)i * DIMD + d];
    for (int off = 32; off > 0; off >>= 1) s += __shfl_down(s, off);
    if (lane == 0) hcls[w] = fmaxf(s + cB1[i], 0.f);
}

// logits + aux write (fused writeaux)
__global__ __launch_bounds__(256) void k_cls2(const float* __restrict__ hcls, const float* __restrict__ cW2,
                                              const float* __restrict__ cB2, const float* __restrict__ aux_acc,
                                              float* __restrict__ out)
{
    if (blockIdx.x == 0 && threadIdx.x == 0) out[NB_ * CCLS] = *aux_acc;
    int w = blockIdx.x * 4 + (threadIdx.x >> 6);
    int lane = threadIdx.x & 63;
    if (w >= NB_ * CCLS) return;
    int b = w / CCLS, c = w % CCLS;
    float s = 0.f;
    for (int d = lane; d < DIMD; d += 64) s += hcls[b * DIMD + d] * cW2[(size_t)c * DIMD + d];
    for (int off = 32; off > 0; off >>= 1) s += __shfl_down(s, off);
    if (lane == 0) out[w] = s + cB2[c];
}

// ---------------- host launch ----------------
extern "C" void kernel_launch(void* const* d_in, const int* in_sizes, int n_in,
                              void* d_out, int out_size, void* d_ws, size_t ws_size,
                              hipStream_t stream)
{
    const int*   input_ids = (const int*)  d_in[0];
    const float* tok_emb   = (const float*)d_in[1];
    const float* pos_emb   = (const float*)d_in[2];
    const float* wqkv      = (const float*)d_in[3];
    const float* bqkv      = (const float*)d_in[4];
    const float* wo        = (const float*)d_in[5];
    const float* bo        = (const float*)d_in[6];
    const float* ln1g      = (const float*)d_in[7];
    const float* ln1b      = (const float*)d_in[8];
    const float* ln2g      = (const float*)d_in[9];
    const float* ln2b      = (const float*)d_in[10];
    const float* dW1       = (const float*)d_in[11];
    const float* dB1       = (const float*)d_in[12];
    const float* dW2       = (const float*)d_in[13];
    const float* dB2       = (const float*)d_in[14];
    const float* mW1       = (const float*)d_in[15];
    const float* mB1       = (const float*)d_in[16];
    const float* mW2       = (const float*)d_in[17];
    const float* mB2       = (const float*)d_in[18];
    const float* gAw       = (const float*)d_in[19];
    const float* gAb       = (const float*)d_in[20];
    const float* gBw       = (const float*)d_in[21];
    const float* gBb       = (const float*)d_in[22];
    const float* cW1       = (const float*)d_in[23];
    const float* cB1       = (const float*)d_in[24];
    const float* cW2       = (const float*)d_in[25];
    const float* cB2       = (const float*)d_in[26];

    float* out = (float*)d_out;
    float* ws  = (float*)d_ws;

    float*  X    = ws + OFF_X;
    ushort* XB   = (ushort*)(ws + OFF_XB);
    ushort* FB   = (ushort*)(ws + OFF_F);
    ushort* QKV  = (ushort*)(ws + OFF_SH);
    ushort* G    = (ushort*)(ws + OFF_SH + (size_t)TOK * 3 * DIMD / 2);
    ushort* Gg   = (ushort*)(ws + OFF_SH);     // FFN GLU'd activations (8704 x 3072 bf16)
    ushort* WQB  = (ushort*)(ws + OFF_WQ);
    ushort* WOB  = (ushort*)(ws + OFF_WOB);
    ushort* W1B  = (ushort*)(ws + OFF_W1B);
    ushort* W2B  = (ushort*)(ws + OFF_W2B);
    float*  REP  = ws + OFF_REP;
    float*  HCLS = ws + OFF_HCLS;
    float*  SUMS3= ws + OFF_STAT;             // 3 x 8 floats
    int*    INTB = (int*)(ws + OFF_INT);
    int*    CNTS3= INTB;                      // 3 x 16 ints
    int*    OFFS = INTB + 48;                 // 5
    int*    CURS = INTB + 53;                 // 4
    int*    NBLK = INTB + 57;                 // 1
    int*    BLKE = INTB + 58;                 // 68
    int*    BLKB = INTB + 126;                // 68
    float*  AUXP = ws + OFF_AUX;
    int*    EID  = (int*)(ws + OFF_EID);
    int*    PERM = (int*)(ws + OFF_PERM);

    k_embed<<<dim3((TOK * DIMD / 4) / 256), 256, 0, stream>>>(
        input_ids, tok_emb, pos_emb, X, XB, SUMS3, CNTS3, AUXP);

    const int nq = 3 * DIMD * DIMD / 8;
    const int no = DIMD * DIMD / 8;
    int di = 0, mi = 0;
    for (int l = 0; l < 6; ++l) {
        const int moe = (l == 1 || l == 3 || l == 5);
        // --- per-layer weight conversion fp32->bf16 (single segmented launch) ---
        {
            const float* s2; const float* s3; int n2, n3;
            if (moe) {
                s2 = mW1 + (size_t)mi * NEXP * FF2 * DIMD;  n2 = NEXP * FF2 * DIMD / 8;
                s3 = mW2 + (size_t)mi * NEXP * DIMD * FFD;  n3 = NEXP * DIMD * FFD / 8;
            } else {
                s2 = dW1 + (size_t)di * FF2 * DIMD;         n2 = FF2 * DIMD / 8;
                s3 = dW2 + (size_t)di * (size_t)DIMD * FFD; n3 = DIMD * FFD / 8;
            }
            int ntot = nq + no + n2 + n3;
            k_cvt4<<<dim3((ntot + 255) / 256), 256, 0, stream>>>(
                wqkv + (size_t)l * 3 * DIMD * DIMD, WQB, nq,
                wo   + (size_t)l * DIMD * DIMD,     WOB, no,
                s2, W1B, n2,
                s3, W2B, n3);
        }
        // QKV projection (bf16 -> bf16)
        k_mm<0,0><<<dim3(3 * DIMD / 128, TOK / 128), 256, 0, stream>>>(
            XB, WQB, bqkv + (size_t)l * 3 * DIMD, QKV, 3 * DIMD, DIMD, DIMD,
            nullptr, nullptr, nullptr, nullptr, nullptr);
        // attention (2 q-tiles per block)
        k_attn<<<dim3(NB_ * NH, SEQ / 128), 256, 0, stream>>>(QKV, G);
        // output projection (bf16 -> bf16 FB)
        k_mm<0,0><<<dim3(DIMD / 128, TOK / 128), 256, 0, stream>>>(
            G, WOB, bo + (size_t)l * DIMD, FB, DIMD, DIMD, DIMD,
            nullptr, nullptr, nullptr, nullptr, nullptr);
        k_ln<<<TOK / 4, 256, 0, stream>>>(X, FB, ln1g + (size_t)l * DIMD, ln1b + (size_t)l * DIMD, XB);

        if (moe) {
            float* SUMS = SUMS3 + mi * 8;
            int*   CNTS = CNTS3 + mi * 16;
            k_gate<<<64, 256, 0, stream>>>(X,
                gAw + (size_t)mi * 2 * DIMD, gAb + (size_t)mi * 2,
                gBw + (size_t)mi * 2 * DIMD, gBb + (size_t)mi * 2,
                SUMS, CNTS, EID);
            k_offsets<<<1, 1, 0, stream>>>(CNTS + 4, OFFS, CURS, NBLK, BLKE, BLKB,
                                           SUMS, CNTS, AUXP);
            k_scatter<<<TOK / 256, 256, 0, stream>>>(EID, OFFS, CURS, PERM);
            k_w1g<1><<<dim3(FFD / 128, 68), 256, 0, stream>>>(
                XB, W1B, mB1 + (size_t)mi * NEXP * FF2, Gg,
                PERM, OFFS, BLKE, BLKB, NBLK);
            k_mm<0,1><<<dim3(DIMD / 128, 68), 256, 0, stream>>>(
                Gg, W2B, mB2 + (size_t)mi * NEXP * DIMD, FB, DIMD, FFD, FFD,
                PERM, OFFS, BLKE, BLKB, NBLK);
            ++mi;
        } else {
            k_w1g<0><<<dim3(FFD / 128, TOK / 128), 256, 0, stream>>>(
                XB, W1B, dB1 + (size_t)di * FF2, Gg,
                nullptr, nullptr, nullptr, nullptr, nullptr);
            k_mm<0,0><<<dim3(DIMD / 128, TOK / 128), 256, 0, stream>>>(
                Gg, W2B, dB2 + (size_t)di * DIMD, FB, DIMD, FFD, FFD,
                nullptr, nullptr, nullptr, nullptr, nullptr);
            ++di;
        }
        k_ln<<<TOK / 4, 256, 0, stream>>>(X, FB, ln2g + (size_t)l * DIMD, ln2b + (size_t)l * DIMD, XB);
    }

    k_rep<<<dim3((NB_ * DIMD + 255) / 256), 256, 0, stream>>>(X, REP);
    k_cls1<<<dim3(NB_ * DIMD / 4), 256, 0, stream>>>(REP, cW1, cB1, HCLS);
    k_cls2<<<dim3((NB_ * CCLS + 3) / 4), 256, 0, stream>>>(HCLS, cW2, cB2, AUXP, out);
}

// Round 18
// 2791.602 us; speedup vs baseline: 1.0967x; 1.0240x over previous
//
#include <hip/hip_runtime.h>
#include <cstddef>

#define TOK   8192
#define DIMD  768
#define NH    12
#define DHD   64
#define SEQ   512
#define NB_   16
#define FFD   3072
#define NEXP  4
#define CCLS  10
#define FF2   (2*FFD)

typedef short bf16x8 __attribute__((ext_vector_type(8)));
typedef float f32x4  __attribute__((ext_vector_type(4)));

// ---------------- workspace layout (float-slot units) ----------------
static const size_t OFF_X    = 0;                                   // (unused, kept for layout stability)
static const size_t OFF_XB   = OFF_X   + (size_t)TOK*DIMD;          // TOK*D bf16 (residual stream)
static const size_t OFF_F    = OFF_XB  + (size_t)TOK*DIMD/2;        // TOK*D bf16 (residual branch)
static const size_t OFF_SH   = OFF_F   + (size_t)TOK*DIMD;          // shared: QKV+attnG | Gglu
static const size_t SH_FL    = (size_t)8704*FF2/2;
static const size_t OFF_WQ   = OFF_SH  + SH_FL;                     // qkv weights bf16
static const size_t OFF_WOB  = OFF_WQ  + (size_t)3*DIMD*DIMD/2;
static const size_t OFF_W1B  = OFF_WOB + (size_t)DIMD*DIMD/2;       // up to 4 experts
static const size_t OFF_W2B  = OFF_W1B + (size_t)NEXP*FF2*DIMD/2;
static const size_t OFF_REP  = OFF_W2B + (size_t)NEXP*DIMD*FFD/2;
static const size_t OFF_HCLS = OFF_REP + (size_t)NB_*DIMD;
static const size_t OFF_STAT = OFF_HCLS+ (size_t)NB_*DIMD;          // 3 x 8 floats (per-MoE-layer sums)
static const size_t OFF_INT  = OFF_STAT+ 24;                        // 200 int slots
static const size_t OFF_AUX  = OFF_INT + 200;
static const size_t OFF_EID  = OFF_AUX + 1;                         // TOK ints
static const size_t OFF_PERM = OFF_EID + TOK;                       // TOK ints
// INT map: CNTS3[0..47] (3x16), OFFS[48..52], CURS[53..56], NBLK[57], BLKE[58..125], BLKB[126..193]

__device__ __forceinline__ ushort f2bf(float f) {
    union { float f; unsigned u; } v; v.f = f;
    unsigned r = v.u + 0x7FFF + ((v.u >> 16) & 1);   // RNE
    return (ushort)(r >> 16);
}
__device__ __forceinline__ float bf2f(ushort u) {
    union { unsigned u; float f; } v; v.u = ((unsigned)u) << 16;
    return v.f;
}
__device__ __forceinline__ void gload16(const void* g, void* l) {
    __builtin_amdgcn_global_load_lds((const __attribute__((address_space(1))) void*)g,
                                     (__attribute__((address_space(3))) void*)l, 16, 0, 0);
}

// chunked-bijective XCD swizzle (column-major walk) — R10-proven
__device__ __forceinline__ void xcd_swizzle_cm(int& bx, int& by)
{
    int gx = gridDim.x, gy = gridDim.y;
    int bid = blockIdx.x * gy + blockIdx.y;
    int nwg = gx * gy;
    int q = nwg >> 3, r8 = nwg & 7;
    int xcd = bid & 7, loc = bid >> 3;
    int lbid = (xcd < r8 ? xcd * (q + 1) : r8 * (q + 1) + (xcd - r8) * q) + loc;
    bx = lbid / gy;
    by = lbid % gy;
}

// ---------------- segmented weight fp32 -> bf16 conversion (one launch per layer) ----------------
__global__ __launch_bounds__(256) void k_cvt4(const float* __restrict__ s0, ushort* __restrict__ d0, int n0,
                                              const float* __restrict__ s1, ushort* __restrict__ d1, int n1,
                                              const float* __restrict__ s2, ushort* __restrict__ d2, int n2,
                                              const float* __restrict__ s3, ushort* __restrict__ d3, int n3)
{
    int i = blockIdx.x * 256 + threadIdx.x;
    const float* s; ushort* d; int j = i;
    if (j < n0) { s = s0; d = d0; }
    else {
        j -= n0;
        if (j < n1) { s = s1; d = d1; }
        else {
            j -= n1;
            if (j < n2) { s = s2; d = d2; }
            else {
                j -= n2;
                if (j >= n3) return;
                s = s3; d = d3;
            }
        }
    }
    float4 x0 = ((const float4*)s)[j * 2];
    float4 x1 = ((const float4*)s)[j * 2 + 1];
    ushort r[8] = { f2bf(x0.x), f2bf(x0.y), f2bf(x0.z), f2bf(x0.w),
                    f2bf(x1.x), f2bf(x1.y), f2bf(x1.z), f2bf(x1.w) };
    ((uint4*)d)[j] = *(uint4*)r;
}

// ---------------- embedding: Xb bf16 + gate-statistics init ----------------
__global__ __launch_bounds__(256) void k_embed(const int* __restrict__ ids,
                                               const float* __restrict__ te,
                                               const float* __restrict__ pe,
                                               ushort* __restrict__ xb,
                                               float* __restrict__ sums3,
                                               int* __restrict__ cnts3,
                                               float* __restrict__ aux)
{
    if (blockIdx.x == 0) {
        int t = threadIdx.x;
        if (t < 24)             sums3[t] = 0.f;
        if (t >= 32 && t < 80)  cnts3[t - 32] = 0;
        if (t == 80)            *aux = 0.f;
    }
    int i = blockIdx.x * 256 + threadIdx.x;
    const int nd4 = DIMD / 4;
    if (i >= TOK * nd4) return;
    int t = i / nd4, d4 = i % nd4;
    int s = t % SEQ;
    int id = ids[t];
    float4 a = ((const float4*)(te + (size_t)id * DIMD))[d4];
    float4 b = ((const float4*)(pe + (size_t)s  * DIMD))[d4];
    float4 o; o.x = a.x + b.x; o.y = a.y + b.y; o.z = a.z + b.z; o.w = a.w + b.w;
    ushort4 ob = make_ushort4(f2bf(o.x), f2bf(o.y), f2bf(o.z), f2bf(o.w));
    *(ushort4*)(xb + (size_t)t * DIMD + d4 * 4) = ob;
}

// ---------------- 128x128 MFMA GEMM (R8/R10-proven 2-barrier loop) ----------------
template<int GATHER, int SCAT>
__global__ __launch_bounds__(256) void k_mm(const ushort* __restrict__ A,
                                            const ushort* __restrict__ Wb,
                                            const float* __restrict__ bias,
                                            ushort* __restrict__ C_,
                                            int N, int K, int lda,
                                            const int* __restrict__ perm,
                                            const int* __restrict__ offs,
                                            const int* __restrict__ blke,
                                            const int* __restrict__ blkb,
                                            const int* __restrict__ nblk)
{
    constexpr int MOE = GATHER || SCAT;
    __shared__ ushort As[2][4096];
    __shared__ ushort Bs[2][4096];
    __shared__ int    toks[128];
    const int tid = threadIdx.x, lane = tid & 63, w = tid >> 6;
    int bx, by;
    xcd_swizzle_cm(bx, by);
    const int n0 = bx * 128, row0 = by * 128;
    const ushort* W = Wb;
    const float*  bi = bias;
    int lb = 0, cnt = 1 << 30;
    if constexpr (MOE) {
        if (by >= *nblk) return;
        int e = blke[by];
        lb = blkb[by];
        int base = offs[e];
        cnt = offs[e + 1] - base;
        W  += (size_t)e * N * K;
        bi += (size_t)e * N;
        if (tid < 128) { int rg = lb + tid; toks[tid] = perm[base + (rg < cnt ? rg : cnt - 1)]; }
        __syncthreads();
    }
    int ar0, ar1;
    if constexpr (GATHER) { ar0 = toks[lane]; ar1 = toks[64 + lane]; }
    else                  { ar0 = row0 + lane; ar1 = row0 + 64 + lane; }
    const ushort* ap0 = A + (size_t)ar0 * lda + w * 8;
    const ushort* ap1 = A + (size_t)ar1 * lda + w * 8;
    const ushort* bp0 = W + (size_t)(n0 + lane) * K + w * 8;
    const ushort* bp1 = W + (size_t)(n0 + 64 + lane) * K + w * 8;

    const int l15 = lane & 15, l4 = lane >> 4;
    const int wm = w >> 1, wn = w & 1;
    f32x4 acc[4][4] = {};

    gload16(ap0, &As[0][w * 1024]);
    gload16(ap1, &As[0][w * 1024 + 512]);
    gload16(bp0, &Bs[0][w * 1024]);
    gload16(bp1, &Bs[0][w * 1024 + 512]);
    __syncthreads();

    const int NT = K / 32;
    int cur = 0;
    for (int t = 0; t < NT; ++t) {
        if (t + 1 < NT) {
            int ko = (t + 1) * 32;
            gload16(ap0 + ko, &As[cur ^ 1][w * 1024]);
            gload16(ap1 + ko, &As[cur ^ 1][w * 1024 + 512]);
            gload16(bp0 + ko, &Bs[cur ^ 1][w * 1024]);
            gload16(bp1 + ko, &Bs[cur ^ 1][w * 1024 + 512]);
        }
        bf16x8 af[4], bf_[4];
#pragma unroll
        for (int i = 0; i < 4; ++i) {
            af[i]  = *(const bf16x8*)&As[cur][l4 * 1024 + (wm * 64 + i * 16 + l15) * 8];
            bf_[i] = *(const bf16x8*)&Bs[cur][l4 * 1024 + (wn * 64 + i * 16 + l15) * 8];
        }
#pragma unroll
        for (int mi = 0; mi < 4; ++mi)
#pragma unroll
            for (int ni = 0; ni < 4; ++ni)
                acc[mi][ni] = __builtin_amdgcn_mfma_f32_16x16x32_bf16(af[mi], bf_[ni], acc[mi][ni], 0, 0, 0);
        __syncthreads();
        cur ^= 1;
    }
#pragma unroll
    for (int ni = 0; ni < 4; ++ni) {
        int col = n0 + wn * 64 + ni * 16 + l15;
        float bb = bi[col];
#pragma unroll
        for (int mi = 0; mi < 4; ++mi) {
            int ri = wm * 64 + mi * 16 + l4 * 4;
#pragma unroll
            for (int r = 0; r < 4; ++r) {
                float o = acc[mi][ni][r] + bb;
                if constexpr (SCAT) {
                    if (lb + ri + r < cnt)
                        C_[(size_t)toks[ri + r] * N + col] = f2bf(o);
                } else {
                    C_[(size_t)(row0 + ri + r) * N + col] = f2bf(o);
                }
            }
        }
    }
}

// ---------------- W1 + GLU fused epilogue (R8 structure) ----------------
template<int MOE>
__global__ __launch_bounds__(256) void k_w1g(const ushort* __restrict__ A,
                                             const ushort* __restrict__ Wb,
                                             const float* __restrict__ bias,
                                             ushort* __restrict__ G,
                                             const int* __restrict__ perm,
                                             const int* __restrict__ offs,
                                             const int* __restrict__ blke,
                                             const int* __restrict__ blkb,
                                             const int* __restrict__ nblk)
{
    __shared__ ushort As[2][4096];
    __shared__ ushort Bs[2][8192];
    __shared__ int    toks[128];
    const int tid = threadIdx.x, lane = tid & 63, w = tid >> 6;
    int bx, by;
    xcd_swizzle_cm(bx, by);
    const int n0 = bx * 128, row0 = by * 128;
    const ushort* W = Wb;
    const float*  bi = bias;
    if constexpr (MOE) {
        if (by >= *nblk) return;
        int e = blke[by];
        W  += (size_t)e * FF2 * DIMD;
        bi += (size_t)e * FF2;
        int base = offs[e], cnt = offs[e + 1] - base, lb = blkb[by];
        if (tid < 128) { int rg = lb + tid; toks[tid] = perm[base + (rg < cnt ? rg : cnt - 1)]; }
        __syncthreads();
    }
    int ar0, ar1;
    if constexpr (MOE) { ar0 = toks[lane]; ar1 = toks[64 + lane]; }
    else               { ar0 = row0 + lane; ar1 = row0 + 64 + lane; }
    const ushort* ap0  = A + (size_t)ar0 * DIMD + w * 8;
    const ushort* ap1  = A + (size_t)ar1 * DIMD + w * 8;
    const ushort* bpa0 = W + (size_t)(n0 + lane) * DIMD + w * 8;
    const ushort* bpa1 = W + (size_t)(n0 + 64 + lane) * DIMD + w * 8;
    const ushort* bpb0 = W + (size_t)(FFD + n0 + lane) * DIMD + w * 8;
    const ushort* bpb1 = W + (size_t)(FFD + n0 + 64 + lane) * DIMD + w * 8;

    const int l15 = lane & 15, l4 = lane >> 4;
    const int wm = w >> 1, wn = w & 1;
    f32x4 accA[4][4] = {}, accB[4][4] = {};

    gload16(ap0,  &As[0][w * 1024]);
    gload16(ap1,  &As[0][w * 1024 + 512]);
    gload16(bpa0, &Bs[0][w * 2048]);
    gload16(bpa1, &Bs[0][w * 2048 + 512]);
    gload16(bpb0, &Bs[0][w * 2048 + 1024]);
    gload16(bpb1, &Bs[0][w * 2048 + 1536]);
    __syncthreads();

    const int NT = DIMD / 32;
    int cur = 0;
    for (int t = 0; t < NT; ++t) {
        if (t + 1 < NT) {
            int ko = (t + 1) * 32;
            gload16(ap0 + ko,  &As[cur ^ 1][w * 1024]);
            gload16(ap1 + ko,  &As[cur ^ 1][w * 1024 + 512]);
            gload16(bpa0 + ko, &Bs[cur ^ 1][w * 2048]);
            gload16(bpa1 + ko, &Bs[cur ^ 1][w * 2048 + 512]);
            gload16(bpb0 + ko, &Bs[cur ^ 1][w * 2048 + 1024]);
            gload16(bpb1 + ko, &Bs[cur ^ 1][w * 2048 + 1536]);
        }
        bf16x8 af[4], ba[4], bb[4];
#pragma unroll
        for (int i = 0; i < 4; ++i) {
            af[i] = *(const bf16x8*)&As[cur][l4 * 1024 + (wm * 64 + i * 16 + l15) * 8];
            ba[i] = *(const bf16x8*)&Bs[cur][l4 * 2048 + (wn * 64 + i * 16 + l15) * 8];
            bb[i] = *(const bf16x8*)&Bs[cur][l4 * 2048 + 1024 + (wn * 64 + i * 16 + l15) * 8];
        }
#pragma unroll
        for (int mi = 0; mi < 4; ++mi)
#pragma unroll
            for (int ni = 0; ni < 4; ++ni) {
                accA[mi][ni] = __builtin_amdgcn_mfma_f32_16x16x32_bf16(af[mi], ba[ni], accA[mi][ni], 0, 0, 0);
                accB[mi][ni] = __builtin_amdgcn_mfma_f32_16x16x32_bf16(af[mi], bb[ni], accB[mi][ni], 0, 0, 0);
            }
        __syncthreads();
        cur ^= 1;
    }
#pragma unroll
    for (int ni = 0; ni < 4; ++ni) {
        int col = n0 + wn * 64 + ni * 16 + l15;
        float fa = bi[col];
        float fb = bi[FFD + col];
#pragma unroll
        for (int mi = 0; mi < 4; ++mi) {
            int ri = wm * 64 + mi * 16 + l4 * 4;
#pragma unroll
            for (int r = 0; r < 4; ++r) {
                float a = accA[mi][ni][r] + fa;
                float b = accB[mi][ni][r] + fb;
                float g = a * (b / (1.f + __expf(-b)));
                G[(size_t)(row0 + ri + r) * FFD + col] = f2bf(g);
            }
        }
    }
}

// ---------------- MFMA flash attention: 2 q-tiles per block (K/V staged once) ----------------
__global__ __launch_bounds__(256) void k_attn(const ushort* __restrict__ qkv, ushort* __restrict__ out)
{
    __shared__ ushort Qs[2][64][72];
    __shared__ ushort Ks[64][72];
    __shared__ ushort Vt[64][72];
    __shared__ ushort Ps[4][16][72];
    const int bh = blockIdx.x;
    const int b = bh / NH, h = bh % NH;
    const int qp = blockIdx.y;                       // q-pair index (0..3)
    const int tid = threadIdx.x, lane = tid & 63, w = tid >> 6;
    const int l15 = lane & 15, l4 = lane >> 4;
    const int t0 = b * SEQ + qp * 128;               // first of 128 q rows
    {
        int r = tid >> 3, c8 = (tid & 7) * 8;
#pragma unroll
        for (int sub = 0; sub < 2; ++sub)
#pragma unroll
            for (int p = 0; p < 2; ++p) {
                int rr = r + p * 32;
                *(uint4*)&Qs[sub][rr][c8] =
                    *(const uint4*)(qkv + (size_t)(t0 + sub * 64 + rr) * 3 * DIMD + h * DHD + c8);
            }
    }
    __syncthreads();
    bf16x8 aq[2][2];
#pragma unroll
    for (int sub = 0; sub < 2; ++sub) {
        aq[sub][0] = *(const bf16x8*)&Qs[sub][w*16 + l15][l4*8];
        aq[sub][1] = *(const bf16x8*)&Qs[sub][w*16 + l15][32 + l4*8];
    }
    f32x4 o[2][4] = {};
    float m[2][4], lsum[2][4];
#pragma unroll
    for (int sub = 0; sub < 2; ++sub)
#pragma unroll
        for (int r = 0; r < 4; ++r) { m[sub][r] = -3.0e38f; lsum[sub][r] = 0.f; }
    for (int kt = 0; kt < SEQ; kt += 64) {
        __syncthreads();
        {
            int r = tid >> 3, c8 = (tid & 7) * 8;
#pragma unroll
            for (int p = 0; p < 2; ++p) {
                int rr = r + p * 32;
                const ushort* kp = qkv + (size_t)(b * SEQ + kt + rr) * 3 * DIMD + DIMD + h * DHD;
                *(uint4*)&Ks[rr][c8] = *(const uint4*)(kp + c8);
                uint4 vv = *(const uint4*)(kp + DIMD + c8);
                const ushort* vs = (const ushort*)&vv;
#pragma unroll
                for (int j = 0; j < 8; ++j) Vt[c8 + j][rr] = vs[j];
            }
        }
        __syncthreads();
#pragma unroll
        for (int sub = 0; sub < 2; ++sub) {
            f32x4 s[4] = {};
#pragma unroll
            for (int kk = 0; kk < 2; ++kk)
#pragma unroll
                for (int ni = 0; ni < 4; ++ni) {
                    bf16x8 bk = *(const bf16x8*)&Ks[ni*16 + l15][kk*32 + l4*8];
                    s[ni] = __builtin_amdgcn_mfma_f32_16x16x32_bf16(aq[sub][kk], bk, s[ni], 0, 0, 0);
                }
            float csc[4];
#pragma unroll
            for (int r = 0; r < 4; ++r) {
                float mx = -3.0e38f;
#pragma unroll
                for (int ni = 0; ni < 4; ++ni) { s[ni][r] *= 0.125f; mx = fmaxf(mx, s[ni][r]); }
                mx = fmaxf(mx, __shfl_xor(mx, 1));
                mx = fmaxf(mx, __shfl_xor(mx, 2));
                mx = fmaxf(mx, __shfl_xor(mx, 4));
                mx = fmaxf(mx, __shfl_xor(mx, 8));
                float nm = fmaxf(m[sub][r], mx);
                float c = __expf(m[sub][r] - nm);
                m[sub][r] = nm;
                float ps = 0.f;
#pragma unroll
                for (int ni = 0; ni < 4; ++ni) { s[ni][r] = __expf(s[ni][r] - nm); ps += s[ni][r]; }
                ps += __shfl_xor(ps, 1);
                ps += __shfl_xor(ps, 2);
                ps += __shfl_xor(ps, 4);
                ps += __shfl_xor(ps, 8);
                lsum[sub][r] = lsum[sub][r] * c + ps;
                csc[r] = c;
#pragma unroll
                for (int ni = 0; ni < 4; ++ni)
                    Ps[w][l4*4 + r][ni*16 + l15] = f2bf(s[ni][r]);
            }
#pragma unroll
            for (int di = 0; di < 4; ++di)
#pragma unroll
                for (int r = 0; r < 4; ++r) o[sub][di][r] *= csc[r];
            bf16x8 ap[2];
            ap[0] = *(const bf16x8*)&Ps[w][l15][l4*8];
            ap[1] = *(const bf16x8*)&Ps[w][l15][32 + l4*8];
#pragma unroll
            for (int kk = 0; kk < 2; ++kk)
#pragma unroll
                for (int di = 0; di < 4; ++di) {
                    bf16x8 bv = *(const bf16x8*)&Vt[di*16 + l15][kk*32 + l4*8];
                    o[sub][di] = __builtin_amdgcn_mfma_f32_16x16x32_bf16(ap[kk], bv, o[sub][di], 0, 0, 0);
                }
        }
    }
#pragma unroll
    for (int sub = 0; sub < 2; ++sub) {
        float inv[4];
#pragma unroll
        for (int r = 0; r < 4; ++r) inv[r] = 1.f / lsum[sub][r];
#pragma unroll
        for (int di = 0; di < 4; ++di)
#pragma unroll
            for (int r = 0; r < 4; ++r)
                out[(size_t)(t0 + sub*64 + w*16 + l4*4 + r) * DIMD + h * DHD + di*16 + l15] =
                    f2bf(o[sub][di][r] * inv[r]);
    }
}

// ---------------- wave-per-row residual + LayerNorm, bf16-only stream (in-place) ----------------
__global__ __launch_bounds__(256) void k_ln(ushort* __restrict__ xb, const ushort* __restrict__ fb,
                                            const float* __restrict__ g, const float* __restrict__ b)
{
    const int t = blockIdx.x * 4 + (threadIdx.x >> 6);
    const int lane = threadIdx.x & 63;
    ushort* xr = xb + (size_t)t * DIMD;
    const ushort* fr = fb + (size_t)t * DIMD;
    float v[12];
    float s = 0.f, s2 = 0.f;
#pragma unroll
    for (int j = 0; j < 12; ++j) {
        int d = lane + j * 64;
        float val = bf2f(xr[d]) + bf2f(fr[d]);
        v[j] = val; s += val; s2 = fmaf(val, val, s2);
    }
#pragma unroll
    for (int off = 1; off < 64; off <<= 1) {
        s  += __shfl_xor(s,  off);
        s2 += __shfl_xor(s2, off);
    }
    const float mean = s * (1.f / DIMD);
    const float var  = s2 * (1.f / DIMD) - mean * mean;
    const float rstd = rsqrtf(var + 1e-5f);
#pragma unroll
    for (int j = 0; j < 12; ++j) {
        int d = lane + j * 64;
        float o = (v[j] - mean) * rstd * g[d] + b[d];
        xr[d] = f2bf(o);
    }
}

// ---------------- MoE gating (bf16 input) ----------------
__global__ __launch_bounds__(256) void k_gate(const ushort* __restrict__ x,
                                              const float* __restrict__ gAw, const float* __restrict__ gAb,
                                              const float* __restrict__ gBw, const float* __restrict__ gBb,
                                              float* __restrict__ sums, int* __restrict__ cnts,
                                              int* __restrict__ e_id)
{
    const int tid = threadIdx.x, lane = tid & 63, wid = tid >> 6;
    const int gw = blockIdx.x * 4 + wid;
    float wA0[12], wA1[12], wB0[12], wB1[12];
#pragma unroll
    for (int i = 0; i < 12; ++i) {
        int d = lane + i * 64;
        wA0[i] = gAw[d]; wA1[i] = gAw[DIMD + d];
        wB0[i] = gBw[d]; wB1[i] = gBw[DIMD + d];
    }
    const float bA0 = gAb[0], bA1 = gAb[1], bB0 = gBb[0], bB1 = gBb[1];
    float sA0 = 0.f, sA1 = 0.f, sB0 = 0.f, sB1 = 0.f;
    int cA1 = 0, cB1 = 0, cE0 = 0, cE1 = 0, cE2 = 0;
    for (int i = 0; i < 32; ++i) {
        int t = gw * 32 + i;
        const ushort* xr = x + (size_t)t * DIMD;
        float a0 = 0.f, a1 = 0.f, b0 = 0.f, b1 = 0.f;
#pragma unroll
        for (int j = 0; j < 12; ++j) {
            float v = bf2f(xr[lane + j * 64]);
            a0 = fmaf(v, wA0[j], a0); a1 = fmaf(v, wA1[j], a1);
            b0 = fmaf(v, wB0[j], b0); b1 = fmaf(v, wB1[j], b1);
        }
#pragma unroll
        for (int off = 1; off < 64; off <<= 1) {
            a0 += __shfl_xor(a0, off); a1 += __shfl_xor(a1, off);
            b0 += __shfl_xor(b0, off); b1 += __shfl_xor(b1, off);
        }
        a0 += bA0; a1 += bA1; b0 += bB0; b1 += bB1;
        int iA = (a1 > a0) ? 1 : 0;
        int iB = (b1 > b0) ? 1 : 0;
        float mA = fmaxf(a0, a1); float eA0 = __expf(a0 - mA), eA1 = __expf(a1 - mA);
        float dA = 1.f / (eA0 + eA1);
        float mB = fmaxf(b0, b1); float eB0 = __expf(b0 - mB), eB1 = __expf(b1 - mB);
        float dB = 1.f / (eB0 + eB1);
        sA0 += eA0 * dA; sA1 += eA1 * dA;
        sB0 += eB0 * dB; sB1 += eB1 * dB;
        cA1 += iA; cB1 += iB;
        int e = iA * 2 + iB;
        cE0 += (e == 0); cE1 += (e == 1); cE2 += (e == 2);
        if (lane == 0) e_id[t] = e;
    }
    __shared__ float fpart[4][4];
    __shared__ int   ipart[4][8];
    if (lane == 0) {
        fpart[wid][0] = sA0; fpart[wid][1] = sA1; fpart[wid][2] = sB0; fpart[wid][3] = sB1;
        ipart[wid][0] = 32 - cA1; ipart[wid][1] = cA1;
        ipart[wid][2] = 32 - cB1; ipart[wid][3] = cB1;
        ipart[wid][4] = cE0; ipart[wid][5] = cE1; ipart[wid][6] = cE2;
        ipart[wid][7] = 32 - cE0 - cE1 - cE2;
    }
    __syncthreads();
    if (tid < 4)  atomicAdd(sums + tid, fpart[0][tid] + fpart[1][tid] + fpart[2][tid] + fpart[3][tid]);
    else if (tid >= 64 && tid < 72) {
        int k = tid - 64;
        atomicAdd(cnts + k, ipart[0][k] + ipart[1][k] + ipart[2][k] + ipart[3][k]);
    }
}

// offsets + block map + fused aux-loss accumulation
__global__ void k_offsets(const int* __restrict__ cntE, int* __restrict__ offs, int* __restrict__ cursor,
                          int* __restrict__ nblk, int* __restrict__ blke, int* __restrict__ blkb,
                          const float* __restrict__ sums, const int* __restrict__ cnts,
                          float* __restrict__ aux_acc)
{
    if (threadIdx.x == 0) {
        int a = 0, nb = 0;
        for (int e = 0; e < NEXP; ++e) {
            offs[e] = a; a += cntE[e]; cursor[e] = 0;
            int blocks = (cntE[e] + 127) >> 7;
            for (int b = 0; b < blocks; ++b) { blke[nb] = e; blkb[nb] = b * 128; ++nb; }
        }
        offs[NEXP] = a;
        *nblk = nb;
        const float invT2 = 1.f / ((float)TOK * (float)TOK);
        float aA = 2.f * (sums[0] * (float)cnts[0] + sums[1] * (float)cnts[1]) * invT2;
        float aB = 2.f * (sums[2] * (float)cnts[2] + sums[3] * (float)cnts[3]) * invT2;
        *aux_acc += aA + aB;
    }
}

__global__ __launch_bounds__(256) void k_scatter(const int* __restrict__ e_id, const int* __restrict__ offs,
                                                 int* __restrict__ cursor, int* __restrict__ perm)
{
    int t = blockIdx.x * 256 + threadIdx.x;
    int lane = threadIdx.x & 63;
    int e = e_id[t];
#pragma unroll
    for (int eo = 0; eo < NEXP; ++eo) {
        unsigned long long m = __ballot(e == eo);
        if (m == 0ULL) continue;
        int leader = __ffsll((long long)m) - 1;
        int base = 0;
        if (lane == leader) base = atomicAdd(cursor + eo, (int)__popcll(m));
        base = __shfl(base, leader);
        if (e == eo) {
            int lower = (int)__popcll(m & ((1ULL << lane) - 1ULL));
            perm[offs[eo] + base + lower] = t;
        }
    }
}

// ---------------- classifier head ----------------
__global__ __launch_bounds__(256) void k_rep(const ushort* __restrict__ x, float* __restrict__ rep)
{
    int i = blockIdx.x * 256 + threadIdx.x;
    if (i >= NB_ * DIMD) return;
    int b = i / DIMD, d = i % DIMD;
    float s = 0.f;
    for (int q = 0; q < SEQ; ++q) s += bf2f(x[((size_t)b * SEQ + q) * DIMD + d]);
    rep[i] = s * (1.f / SEQ);
}

__global__ __launch_bounds__(256) void k_cls1(const float* __restrict__ rep, const float* __restrict__ cW1,
                                              const float* __restrict__ cB1, float* __restrict__ hcls)
{
    int w = blockIdx.x * 4 + (threadIdx.x >> 6);
    int lane = threadIdx.x & 63;
    if (w >= NB_ * DIMD) return;
    int b = w / DIMD, i = w % DIMD;
    float s = 0.f;
    for (int d = lane; d < DIMD; d += 64) s += rep[b * DIMD + d] * cW1[(size_t)i * DIMD + d];
    for (int off = 32; off > 0; off >>= 1) s += __shfl_down(s, off);
    if (lane == 0) hcls[w] = fmaxf(s + cB1[i], 0.f);
}

// logits + aux write (fused writeaux)
__global__ __launch_bounds__(256) void k_cls2(const float* __restrict__ hcls, const float* __restrict__ cW2,
                                              const float* __restrict__ cB2, const float* __restrict__ aux_acc,
                                              float* __restrict__ out)
{
    if (blockIdx.x == 0 && threadIdx.x == 0) out[NB_ * CCLS] = *aux_acc;
    int w = blockIdx.x * 4 + (threadIdx.x >> 6);
    int lane = threadIdx.x & 63;
    if (w >= NB_ * CCLS) return;
    int b = w / CCLS, c = w % CCLS;
    float s = 0.f;
    for (int d = lane; d < DIMD; d += 64) s += hcls[b * DIMD + d] * cW2[(size_t)c * DIMD + d];
    for (int off = 32; off > 0; off >>= 1) s += __shfl_down(s, off);
    if (lane == 0) out[w] = s + cB2[c];
}

// ---------------- host launch ----------------
extern "C" void kernel_launch(void* const* d_in, const int* in_sizes, int n_in,
                              void* d_out, int out_size, void* d_ws, size_t ws_size,
                              hipStream_t stream)
{
    const int*   input_ids = (const int*)  d_in[0];
    const float* tok_emb   = (const float*)d_in[1];
    const float* pos_emb   = (const float*)d_in[2];
    const float* wqkv      = (const float*)d_in[3];
    const float* bqkv      = (const float*)d_in[4];
    const float* wo        = (const float*)d_in[5];
    const float* bo        = (const float*)d_in[6];
    const float* ln1g      = (const float*)d_in[7];
    const float* ln1b      = (const float*)d_in[8];
    const float* ln2g      = (const float*)d_in[9];
    const float* ln2b      = (const float*)d_in[10];
    const float* dW1       = (const float*)d_in[11];
    const float* dB1       = (const float*)d_in[12];
    const float* dW2       = (const float*)d_in[13];
    const float* dB2       = (const float*)d_in[14];
    const float* mW1       = (const float*)d_in[15];
    const float* mB1       = (const float*)d_in[16];
    const float* mW2       = (const float*)d_in[17];
    const float* mB2       = (const float*)d_in[18];
    const float* gAw       = (const float*)d_in[19];
    const float* gAb       = (const float*)d_in[20];
    const float* gBw       = (const float*)d_in[21];
    const float* gBb       = (const float*)d_in[22];
    const float* cW1       = (const float*)d_in[23];
    const float* cB1       = (const float*)d_in[24];
    const float* cW2       = (const float*)d_in[25];
    const float* cB2       = (const float*)d_in[26];

    float* out = (float*)d_out;
    float* ws  = (float*)d_ws;

    ushort* XB   = (ushort*)(ws + OFF_XB);
    ushort* FB   = (ushort*)(ws + OFF_F);
    ushort* QKV  = (ushort*)(ws + OFF_SH);
    ushort* G    = (ushort*)(ws + OFF_SH + (size_t)TOK * 3 * DIMD / 2);
    ushort* Gg   = (ushort*)(ws + OFF_SH);     // FFN GLU'd activations (8704 x 3072 bf16)
    ushort* WQB  = (ushort*)(ws + OFF_WQ);
    ushort* WOB  = (ushort*)(ws + OFF_WOB);
    ushort* W1B  = (ushort*)(ws + OFF_W1B);
    ushort* W2B  = (ushort*)(ws + OFF_W2B);
    float*  REP  = ws + OFF_REP;
    float*  HCLS = ws + OFF_HCLS;
    float*  SUMS3= ws + OFF_STAT;             // 3 x 8 floats
    int*    INTB = (int*)(ws + OFF_INT);
    int*    CNTS3= INTB;                      // 3 x 16 ints
    int*    OFFS = INTB + 48;                 // 5
    int*    CURS = INTB + 53;                 // 4
    int*    NBLK = INTB + 57;                 // 1
    int*    BLKE = INTB + 58;                 // 68
    int*    BLKB = INTB + 126;                // 68
    float*  AUXP = ws + OFF_AUX;
    int*    EID  = (int*)(ws + OFF_EID);
    int*    PERM = (int*)(ws + OFF_PERM);

    k_embed<<<dim3((TOK * DIMD / 4) / 256), 256, 0, stream>>>(
        input_ids, tok_emb, pos_emb, XB, SUMS3, CNTS3, AUXP);

    const int nq = 3 * DIMD * DIMD / 8;
    const int no = DIMD * DIMD / 8;
    int di = 0, mi = 0;
    for (int l = 0; l < 6; ++l) {
        const int moe = (l == 1 || l == 3 || l == 5);
        // --- per-layer weight conversion fp32->bf16 (single segmented launch) ---
        {
            const float* s2; const float* s3; int n2, n3;
            if (moe) {
                s2 = mW1 + (size_t)mi * NEXP * FF2 * DIMD;  n2 = NEXP * FF2 * DIMD / 8;
                s3 = mW2 + (size_t)mi * NEXP * DIMD * FFD;  n3 = NEXP * DIMD * FFD / 8;
            } else {
                s2 = dW1 + (size_t)di * FF2 * DIMD;         n2 = FF2 * DIMD / 8;
                s3 = dW2 + (size_t)di * (size_t)DIMD * FFD; n3 = DIMD * FFD / 8;
            }
            int ntot = nq + no + n2 + n3;
            k_cvt4<<<dim3((ntot + 255) / 256), 256, 0, stream>>>(
                wqkv + (size_t)l * 3 * DIMD * DIMD, WQB, nq,
                wo   + (size_t)l * DIMD * DIMD,     WOB, no,
                s2, W1B, n2,
                s3, W2B, n3);
        }
        // QKV projection (bf16 -> bf16)
        k_mm<0,0><<<dim3(3 * DIMD / 128, TOK / 128), 256, 0, stream>>>(
            XB, WQB, bqkv + (size_t)l * 3 * DIMD, QKV, 3 * DIMD, DIMD, DIMD,
            nullptr, nullptr, nullptr, nullptr, nullptr);
        // attention (2 q-tiles per block)
        k_attn<<<dim3(NB_ * NH, SEQ / 128), 256, 0, stream>>>(QKV, G);
        // output projection (bf16 -> bf16 FB)
        k_mm<0,0><<<dim3(DIMD / 128, TOK / 128), 256, 0, stream>>>(
            G, WOB, bo + (size_t)l * DIMD, FB, DIMD, DIMD, DIMD,
            nullptr, nullptr, nullptr, nullptr, nullptr);
        k_ln<<<TOK / 4, 256, 0, stream>>>(XB, FB, ln1g + (size_t)l * DIMD, ln1b + (size_t)l * DIMD);

        if (moe) {
            float* SUMS = SUMS3 + mi * 8;
            int*   CNTS = CNTS3 + mi * 16;
            k_gate<<<64, 256, 0, stream>>>(XB,
                gAw + (size_t)mi * 2 * DIMD, gAb + (size_t)mi * 2,
                gBw + (size_t)mi * 2 * DIMD, gBb + (size_t)mi * 2,
                SUMS, CNTS, EID);
            k_offsets<<<1, 1, 0, stream>>>(CNTS + 4, OFFS, CURS, NBLK, BLKE, BLKB,
                                           SUMS, CNTS, AUXP);
            k_scatter<<<TOK / 256, 256, 0, stream>>>(EID, OFFS, CURS, PERM);
            k_w1g<1><<<dim3(FFD / 128, 68), 256, 0, stream>>>(
                XB, W1B, mB1 + (size_t)mi * NEXP * FF2, Gg,
                PERM, OFFS, BLKE, BLKB, NBLK);
            k_mm<0,1><<<dim3(DIMD / 128, 68), 256, 0, stream>>>(
                Gg, W2B, mB2 + (size_t)mi * NEXP * DIMD, FB, DIMD, FFD, FFD,
                PERM, OFFS, BLKE, BLKB, NBLK);
            ++mi;
        } else {
            k_w1g<0><<<dim3(FFD / 128, TOK / 128), 256, 0, stream>>>(
                XB, W1B, dB1 + (size_t)di * FF2, Gg,
                nullptr, nullptr, nullptr, nullptr, nullptr);
            k_mm<0,0><<<dim3(DIMD / 128, TOK / 128), 256, 0, stream>>>(
                Gg, W2B, dB2 + (size_t)di * DIMD, FB, DIMD, FFD, FFD,
                nullptr, nullptr, nullptr, nullptr, nullptr);
            ++di;
        }
        k_ln<<<TOK / 4, 256, 0, stream>>>(XB, FB, ln2g + (size_t)l * DIMD, ln2b + (size_t)l * DIMD);
    }

    k_rep<<<dim3((NB_ * DIMD + 255) / 256), 256, 0, stream>>>(XB, REP);
    k_cls1<<<dim3(NB_ * DIMD / 4), 256, 0, stream>>>(REP, cW1, cB1, HCLS);
    k_cls2<<<dim3((NB_ * CCLS + 3) / 4), 256, 0, stream>>>(HCLS, cW2, cB2, AUXP, out);
}